// Round 3
// baseline (71732.471 us; speedup 1.0000x reference)
//
#include <hip/hip_runtime.h>

// ---------------------------------------------------------------------------
// Shapes
// ---------------------------------------------------------------------------
#define B_  128
#define T_  512

typedef unsigned short u16;
typedef unsigned int   u32;
typedef __attribute__((ext_vector_type(8))) __bf16 bf16x8;
typedef __attribute__((ext_vector_type(4))) float  f32x4;

static __device__ __forceinline__ u16 f2bf(float f){
  u32 u = __float_as_uint(f);
  return (u16)((u + 0x7fffu + ((u >> 16) & 1u)) >> 16);
}
static __device__ __forceinline__ float bf2f(u16 s){ return __uint_as_float(((u32)s) << 16); }

static __device__ __forceinline__ void gll16(const void* g, void* l){
  __builtin_amdgcn_global_load_lds((const __attribute__((address_space(1))) u32*)g,
                                   (__attribute__((address_space(3))) u32*)l, 16, 0, 0);
}

// per-batch-group barrier: 64 WGs, monotonically increasing epoch flag
static __device__ __forceinline__ void gbar(int* cnt, int* flag, int target){
  __syncthreads();
  if (threadIdx.x == 0){
    int old = __hip_atomic_fetch_add(cnt, 1, __ATOMIC_ACQ_REL, __HIP_MEMORY_SCOPE_AGENT);
    if (old == 63){
      __hip_atomic_store(cnt, 0, __ATOMIC_RELAXED, __HIP_MEMORY_SCOPE_AGENT);
      __hip_atomic_store(flag, target, __ATOMIC_RELEASE, __HIP_MEMORY_SCOPE_AGENT);
    } else {
      while (__hip_atomic_load(flag, __ATOMIC_RELAXED, __HIP_MEMORY_SCOPE_AGENT) < target)
        __builtin_amdgcn_s_sleep(1);
      (void)__hip_atomic_load(flag, __ATOMIC_ACQUIRE, __HIP_MEMORY_SCOPE_AGENT);
    }
  }
  __syncthreads();
}

// ---------------------------------------------------------------------------
// Weight prep: W[K][2048] f32 -> transposed hi/lo bf16 planes [2048][K]
// ---------------------------------------------------------------------------
__global__ __launch_bounds__(256) void wsplit(const float* __restrict__ src,
                                              u16* __restrict__ dhi, u16* __restrict__ dlo, int K){
  __shared__ float t[32][33];
  const int k0 = (int)blockIdx.x << 5, j0 = (int)blockIdx.y << 5;
  const int tx = (int)threadIdx.x & 31, ty = (int)threadIdx.x >> 5;
#pragma unroll
  for (int i = 0; i < 4; ++i){
    int k = ty + (i << 3);
    t[k][tx] = src[(size_t)(k0 + k) * 2048 + j0 + tx];
  }
  __syncthreads();
#pragma unroll
  for (int i = 0; i < 4; ++i){
    int j = ty + (i << 3);
    float v = t[tx][j];
    u16 hi = f2bf(v);
    size_t di = (size_t)(j0 + j) * K + k0 + tx;
    dhi[di] = hi;
    if (dlo) dlo[di] = f2bf(v - bf2f(hi));
  }
}

__global__ void misc_init(int* bars){ int t = (int)threadIdx.x; if (t < 16) bars[t] = 0; }

__global__ void diag_k(float* out, float v){ if (threadIdx.x < 512) out[threadIdx.x] = v; }

// ---------------------------------------------------------------------------
// Projection GEMM: xp rows (+)= A rows @ W + bias.  M=128 rows per block
// (128/TC batches x TC timesteps), N-tile 128, BK=64, double-buffered LDS.
// ---------------------------------------------------------------------------
struct ProjArgs {
  const u16* ah; const u16* al;
  const u16* wh; const u16* wl;
  long wstride;
  const float* bias;
  float* xp;
  int t0, dir, accum, lg, sb;   // lg = log2(TC), sb = 7 - lg
};

template<int HSLO, int WLO>
__global__ __launch_bounds__(256, 1) void proj_gemm(ProjArgs p){
  extern __shared__ char smem[];          // 2 x 65536
  const int mt = (int)blockIdx.x;
  const int nt = (int)blockIdx.y;
  const int tid = (int)threadIdx.x;
  const int w = tid >> 6, lane = tid & 63;
  const int wm = w & 1, wn = w >> 1;
  const int l15 = lane & 15, l4 = lane >> 4;
  const int tcm1 = (1 << p.lg) - 1;
  const int b0 = mt << p.sb;

  f32x4 acc[4][4];
#pragma unroll
  for (int m2 = 0; m2 < 4; ++m2)
#pragma unroll
    for (int n2 = 0; n2 < 4; ++n2) acc[m2][n2] = (f32x4){0.f,0.f,0.f,0.f};

  const u16* gsrc = nullptr;
  if (w == 0) gsrc = p.ah;
  else if (w == 1) { if constexpr (HSLO) gsrc = p.al; }
  else if (w == 2) gsrc = p.wh;
  else { if constexpr (WLO) gsrc = p.wl; }

  auto do_stage = [&](int ks, int buf){
    if (!gsrc) return;
    char* base = smem + (buf << 16) + (w << 14);
#pragma unroll
    for (int ii = 0; ii < 16; ++ii){
      int r = (ii << 3) + (lane >> 3);
      int co = ((lane & 7) << 4) ^ ((r & 7) << 4);
      size_t rowoff;
      if (w < 2){
        int grow = (b0 + (r >> p.lg)) * T_ + p.t0 + p.dir * (r & tcm1);
        rowoff = ((size_t)grow) << 10;
      } else {
        rowoff = ((size_t)((nt << 7) + r)) * ((size_t)p.wstride << 1);
      }
      gll16((const char*)gsrc + rowoff + (ks << 7) + co, base + (ii << 10));
    }
  };

  do_stage(0, 0);
  for (int ks = 0; ks < 8; ++ks){
    __syncthreads();
    if (ks < 7) do_stage(ks + 1, (ks + 1) & 1);
    const char* bb = smem + ((ks & 1) << 16);
    const char* Ah = bb;
    const char* Al = bb + 16384;
    const char* Wh = bb + 32768;
    const char* Wl = bb + 49152;
#pragma unroll
    for (int kk = 0; kk < 2; ++kk){
      bf16x8 ahf[4], alf[4];
#pragma unroll
      for (int m2 = 0; m2 < 4; ++m2){
        int row = (wm << 6) + (m2 << 4) + l15;
        int off = (row << 7) + (((kk << 6) + (l4 << 4)) ^ ((row & 7) << 4));
        ahf[m2] = *(const bf16x8*)(Ah + off);
        if constexpr (HSLO) alf[m2] = *(const bf16x8*)(Al + off);
      }
#pragma unroll
      for (int n2 = 0; n2 < 4; ++n2){
        int col = (wn << 6) + (n2 << 4) + l15;
        int off = (col << 7) + (((kk << 6) + (l4 << 4)) ^ ((col & 7) << 4));
        bf16x8 bh = *(const bf16x8*)(Wh + off);
        bf16x8 bl;
        if constexpr (WLO) bl = *(const bf16x8*)(Wl + off);
#pragma unroll
        for (int m2 = 0; m2 < 4; ++m2){
          acc[m2][n2] = __builtin_amdgcn_mfma_f32_16x16x32_bf16(ahf[m2], bh, acc[m2][n2], 0,0,0);
          if constexpr (WLO)
            acc[m2][n2] = __builtin_amdgcn_mfma_f32_16x16x32_bf16(ahf[m2], bl, acc[m2][n2], 0,0,0);
          if constexpr (HSLO)
            acc[m2][n2] = __builtin_amdgcn_mfma_f32_16x16x32_bf16(alf[m2], bh, acc[m2][n2], 0,0,0);
        }
      }
    }
  }
#pragma unroll
  for (int n2 = 0; n2 < 4; ++n2){
    int gcol = (nt << 7) + (wn << 6) + (n2 << 4) + l15;
    float bs = p.bias ? p.bias[gcol] : 0.f;
#pragma unroll
    for (int m2 = 0; m2 < 4; ++m2){
#pragma unroll
      for (int i = 0; i < 4; ++i){
        int row = (wm << 6) + (m2 << 4) + (l4 << 2) + i;
        size_t idx = (((size_t)(mt << 7) + row) << 11) + gcol;
        float v = acc[m2][n2][i] + bs;
        if (p.accum) v += p.xp[idx];
        p.xp[idx] = v;
      }
    }
  }
}

// ---------------------------------------------------------------------------
// Persistent LSTM scan: 256 WGs = 4 batch-groups(32 rows) x 64 unit-groups(8 units)
// ---------------------------------------------------------------------------
struct ScanArgs {
  const u16* wh_hi; const u16* wh_lo;   // [2048][512] transposed planes
  const float* xp;
  const float* x; const float* wx1; const float* b1;
  u16* hs_hi; u16* hs_lo;
  u16* hc_hi; u16* hc_lo;               // [2][B][512] exchange, always hi+lo
  float* cbuf;
  int* bcnt; int* bflag;
  int t0, dir, nsteps, first, ep0, is1, lg;
};

template<int HSLO, int WLO>
__global__ __launch_bounds__(256, 1) void lstm_scan(ScanArgs a){
  extern __shared__ char smem[];
  u16* whh = (u16*)(smem);
  u16* whl = (u16*)(smem + 32768);
  u16* hsh = (u16*)(smem + 65536);
  u16* hsl = (u16*)(smem + 98304);
  float* zb = (float*)(smem + 131072);  // [32][33]

  const int bid = (int)blockIdx.x;
  const int bg = bid >> 6, ug = bid & 63;
  const int b0 = bg << 5, u0 = ug << 3;
  const int tid = (int)threadIdx.x;
  const int w = tid >> 6, lane = tid & 63;
  const int mt = w & 1, nt = w >> 1;
  const int l15 = lane & 15, l4 = lane >> 4;

  // stage Wh slice once (local col c -> global col (c/8)*512 + u0 + c%8)
  for (int r = w * 8; r < w * 8 + 8; ++r){
    int gc = ((r >> 3) << 9) + u0 + (r & 7);
    int co = (lane << 4) ^ ((r & 7) << 4);
    gll16((const char*)(a.wh_hi + ((size_t)gc << 9)) + co, (char*)whh + (r << 10));
    if constexpr (WLO)
      gll16((const char*)(a.wh_lo + ((size_t)gc << 9)) + co, (char*)whl + (r << 10));
  }

  const int b_l = tid >> 3, q = tid & 7;
  const int gb = b0 + b_l, gu = u0 + q;
  int ep = a.ep0;
  float c_reg;
  if (a.first){
    int pz = a.t0 & 1;
    a.hc_hi[((size_t)pz << 16) + (gb << 9) + gu] = 0;
    a.hc_lo[((size_t)pz << 16) + (gb << 9) + gu] = 0;
    c_reg = 0.f;
    ++ep;
    gbar(a.bcnt + bg, a.bflag + bg, ep);
  } else {
    c_reg = a.cbuf[(gb << 9) + gu];
  }

  for (int tt = 0; tt < a.nsteps; ++tt){
    int gt = a.t0 + a.dir * tt;
    int par = gt & 1;

    float xg[4];
    if (a.is1){
      float4 xw = *(const float4*)(a.x + (((size_t)gb * T_ + gt) << 2));
#pragma unroll
      for (int g2 = 0; g2 < 4; ++g2){
        int cc = (g2 << 9) + gu;
        xg[g2] = a.b1[cc] + xw.x * a.wx1[cc] + xw.y * a.wx1[2048 + cc]
                          + xw.z * a.wx1[4096 + cc] + xw.w * a.wx1[6144 + cc];
      }
    } else {
      const float* xr = a.xp + (((size_t)((gb << a.lg) + tt)) << 11) + gu;
      xg[0] = xr[0]; xg[1] = xr[512]; xg[2] = xr[1024]; xg[3] = xr[1536];
    }

    // stage h_cur[par] rows b0..b0+31 (hi/lo)
    {
      const size_t pb = ((size_t)par << 16);
      for (int r = w * 8; r < w * 8 + 8; ++r){
        int co = (lane << 4) ^ ((r & 7) << 4);
        gll16((const char*)(a.hc_hi + pb + ((size_t)(b0 + r) << 9)) + co, (char*)hsh + (r << 10));
        gll16((const char*)(a.hc_lo + pb + ((size_t)(b0 + r) << 9)) + co, (char*)hsl + (r << 10));
      }
    }
    __syncthreads();

    // z-tile: wave (mt,nt) computes 16x16 of [32 rows x 32 local cols]
    f32x4 acc = (f32x4){0.f,0.f,0.f,0.f};
    {
      int arow = (mt << 4) + l15;
      int brow = (nt << 4) + l15;
      int abase = arow << 10, aswz = (arow & 7) << 4;
      int bbase = brow << 10, bswz = (brow & 7) << 4;
      int kof = l4 << 4;
#pragma unroll
      for (int j = 0; j < 16; ++j){
        int ao = abase + (((j << 6) + kof) ^ aswz);
        int bo = bbase + (((j << 6) + kof) ^ bswz);
        bf16x8 ah = *(const bf16x8*)((const char*)hsh + ao);
        bf16x8 al = *(const bf16x8*)((const char*)hsl + ao);
        bf16x8 bh = *(const bf16x8*)((const char*)whh + bo);
        acc = __builtin_amdgcn_mfma_f32_16x16x32_bf16(ah, bh, acc, 0,0,0);
        if constexpr (WLO){
          bf16x8 bl = *(const bf16x8*)((const char*)whl + bo);
          acc = __builtin_amdgcn_mfma_f32_16x16x32_bf16(ah, bl, acc, 0,0,0);
        }
        acc = __builtin_amdgcn_mfma_f32_16x16x32_bf16(al, bh, acc, 0,0,0);
      }
    }
    {
      int zr = (mt << 4) + (l4 << 2);
      int zc = (nt << 4) + l15;
#pragma unroll
      for (int i = 0; i < 4; ++i) zb[(zr + i) * 33 + zc] = acc[i];
    }
    __syncthreads();

    {
      float zi = zb[b_l * 33 + q]      + xg[0];
      float zf = zb[b_l * 33 + 8 + q]  + xg[1];
      float zg = zb[b_l * 33 + 16 + q] + xg[2];
      float zo = zb[b_l * 33 + 24 + q] + xg[3];
      float ig = 1.f / (1.f + expf(-zi));
      float fg = 1.f / (1.f + expf(-zf));
      float gg = tanhf(zg);
      float og = 1.f / (1.f + expf(-zo));
      c_reg = fg * c_reg + ig * gg;
      float h = og * tanhf(c_reg);
      u16 hh = f2bf(h);
      u16 hl = f2bf(h - bf2f(hh));
      int pn = par ^ 1;
      a.hc_hi[((size_t)pn << 16) + (gb << 9) + gu] = hh;
      a.hc_lo[((size_t)pn << 16) + (gb << 9) + gu] = hl;
      size_t si = (((size_t)gb * T_ + gt) << 9) + gu;
      a.hs_hi[si] = hh;
      if constexpr (HSLO) a.hs_lo[si] = hl;
    }
    ++ep;
    gbar(a.bcnt + bg, a.bflag + bg, ep);
  }
  a.cbuf[(gb << 9) + gu] = c_reg;
}

// ---------------------------------------------------------------------------
// Final dense head
// ---------------------------------------------------------------------------
template<int HSLO>
__global__ __launch_bounds__(512) void dense_k(const u16* __restrict__ hhi, const u16* __restrict__ hlo,
                                               const float* __restrict__ wd, const float* __restrict__ bd,
                                               float* __restrict__ out){
  int tid = (int)threadIdx.x;
  int b = tid >> 2, o = tid & 3;
  const u16* ph = hhi + (((size_t)b * T_ + (T_ - 1)) << 9);
  const u16* pl = hlo + (((size_t)b * T_ + (T_ - 1)) << 9);
  float s = 0.f;
  for (int u = 0; u < 512; ++u){
    float h = bf2f(ph[u]);
    if constexpr (HSLO) h += bf2f(pl[u]);
    s += h * wd[(u << 2) + o];
  }
  out[(b << 2) + o] = s + bd[o];
}

// ---------------------------------------------------------------------------
// Host
// ---------------------------------------------------------------------------
struct HostCtx {
  const float* x; const float* wx1; const float* b1;
  const float* srcW[8];
  const float* Wx4;
  const float* b2; const float* bf3; const float* bb3; const float* b4;
  const float* Wd; const float* bd;
  u16* wth[8]; u16* wtl[8];
  u16* wx4h; u16* wx4l;
  float* xp;
  u16 *PAh, *PAl, *PBh, *PBl, *hch, *hcl;
  float* cbuf; int* bars;
  float* out;
  int tc, lg;
};

template<int HSLO, int WLO>
static void run_pipeline(const HostCtx& C, hipStream_t stream){
  hipFuncSetAttribute((const void*)&lstm_scan<HSLO,WLO>, hipFuncAttributeMaxDynamicSharedMemorySize, 139264);
  hipFuncSetAttribute((const void*)&proj_gemm<HSLO,WLO>, hipFuncAttributeMaxDynamicSharedMemorySize, 131072);

  for (int i = 0; i < 8; ++i)
    hipLaunchKernelGGL(wsplit, dim3(16, 64), dim3(256), 0, stream, C.srcW[i], C.wth[i], WLO ? C.wtl[i] : nullptr, 512);
  hipLaunchKernelGGL(wsplit, dim3(32, 64), dim3(256), 0, stream, C.Wx4, C.wx4h, WLO ? C.wx4l : nullptr, 1024);
  hipLaunchKernelGGL(misc_init, dim3(1), dim3(64), 0, stream, C.bars);

  const int tc = C.tc, lg = C.lg, NC = 512 / tc, sb = 7 - lg;
  int ep = 0;

  auto scan = [&](int wi, const float* xp_, int is1, u16* hsh_, u16* hsl_, int t0, int dir, int first){
    ScanArgs sa;
    sa.wh_hi = C.wth[wi]; sa.wh_lo = C.wtl[wi]; sa.xp = xp_;
    sa.x = C.x; sa.wx1 = C.wx1; sa.b1 = C.b1;
    sa.hs_hi = hsh_; sa.hs_lo = hsl_; sa.hc_hi = C.hch; sa.hc_lo = C.hcl;
    sa.cbuf = C.cbuf; sa.bcnt = C.bars; sa.bflag = C.bars + 4;
    sa.t0 = t0; sa.dir = dir; sa.nsteps = tc; sa.first = first; sa.ep0 = ep; sa.is1 = is1; sa.lg = lg;
    void* args[] = { &sa };
    hipLaunchCooperativeKernel((const void*)&lstm_scan<HSLO,WLO>, dim3(256), dim3(256), args, 135296u, stream);
    ep += tc + (first ? 1 : 0);
  };
  auto proj = [&](const u16* ah_, const u16* al_, const u16* wh_, const u16* wl_, long wstr,
                  const float* bias_, int t0, int dir, int accum){
    ProjArgs pa;
    pa.ah = ah_; pa.al = al_; pa.wh = wh_; pa.wl = wl_; pa.wstride = wstr;
    pa.bias = bias_; pa.xp = C.xp; pa.t0 = t0; pa.dir = dir; pa.accum = accum; pa.lg = lg; pa.sb = sb;
    hipLaunchKernelGGL(HIP_KERNEL_NAME(proj_gemm<HSLO,WLO>), dim3(tc, 16), dim3(256), 131072, stream, pa);
  };

  for (int c = 0; c < NC; ++c)
    scan(0, nullptr, 1, C.PAh, C.PAl, c * tc, 1, c == 0);
  for (int c = 0; c < NC; ++c){
    proj(C.PAh, C.PAl, C.wth[1], C.wtl[1], 512, C.b2, c * tc, 1, 0);
    scan(2, C.xp, 0, C.PAh, C.PAl, c * tc, 1, c == 0);
  }
  for (int c = 0; c < NC; ++c){
    proj(C.PAh, C.PAl, C.wth[3], C.wtl[3], 512, C.bf3, c * tc, 1, 0);
    scan(4, C.xp, 0, C.PBh, C.PBl, c * tc, 1, c == 0);
  }
  for (int c = 0; c < NC; ++c){
    int t0 = 511 - c * tc;
    proj(C.PAh, C.PAl, C.wth[5], C.wtl[5], 512, C.bb3, t0, -1, 0);
    scan(6, C.xp, 0, C.PAh, C.PAl, t0, -1, c == 0);
  }
  for (int c = 0; c < NC; ++c){
    proj(C.PBh, C.PBl, C.wx4h, C.wx4l, 1024, C.b4, c * tc, 1, 0);
    proj(C.PAh, C.PAl, C.wx4h + 512, WLO ? (C.wx4l + 512) : nullptr, 1024, nullptr, c * tc, 1, 1);
    scan(7, C.xp, 0, C.PBh, C.PBl, c * tc, 1, c == 0);
  }
  hipLaunchKernelGGL(HIP_KERNEL_NAME(dense_k<HSLO>), dim3(1), dim3(512), 0, stream, C.PBh, C.PBl, C.Wd, C.bd, C.out);
}

extern "C" void kernel_launch(void* const* d_in, const int* in_sizes, int n_in,
                              void* d_out, int out_size, void* d_ws, size_t ws_size,
                              hipStream_t stream){
  (void)in_sizes; (void)n_in; (void)out_size;
  HostCtx C;
  C.x   = (const float*)d_in[0];
  C.wx1 = (const float*)d_in[1];
  C.b1  = (const float*)d_in[3];
  C.srcW[0] = (const float*)d_in[2];   // Wh1
  C.srcW[1] = (const float*)d_in[4];   // Wx2
  C.srcW[2] = (const float*)d_in[5];   // Wh2
  C.srcW[3] = (const float*)d_in[7];   // Wxf3
  C.srcW[4] = (const float*)d_in[8];   // Whf3
  C.srcW[5] = (const float*)d_in[10];  // Wxb3
  C.srcW[6] = (const float*)d_in[11];  // Whb3
  C.srcW[7] = (const float*)d_in[14];  // Wh4
  C.b2  = (const float*)d_in[6];
  C.bf3 = (const float*)d_in[9];
  C.bb3 = (const float*)d_in[12];
  C.Wx4 = (const float*)d_in[13];
  C.b4  = (const float*)d_in[15];
  C.Wd  = (const float*)d_in[16];
  C.bd  = (const float*)d_in[17];
  C.out = (float*)d_out;

  struct Tier { int tc, hslo, wlo; };
  const Tier tiers[5] = { {128,1,1}, {64,1,1}, {64,0,1}, {32,0,1}, {32,0,0} };

  auto layout = [&](Tier t)->size_t{
    size_t off = 0;
    auto alloc = [&](size_t sz)->char*{
      char* pp = (char*)d_ws + off; off += sz; off = (off + 255) & ~(size_t)255; return pp;
    };
    for (int i = 0; i < 8; ++i){
      C.wth[i] = (u16*)alloc(2097152);
      C.wtl[i] = t.wlo ? (u16*)alloc(2097152) : nullptr;
    }
    C.wx4h = (u16*)alloc(4194304);
    C.wx4l = t.wlo ? (u16*)alloc(4194304) : nullptr;
    C.xp = (float*)alloc((size_t)B_ * t.tc * 2048 * 4);
    C.PAh = (u16*)alloc(67108864);
    C.PAl = t.hslo ? (u16*)alloc(67108864) : nullptr;
    C.PBh = (u16*)alloc(67108864);
    C.PBl = t.hslo ? (u16*)alloc(67108864) : nullptr;
    C.hch = (u16*)alloc(262144);
    C.hcl = (u16*)alloc(262144);
    C.cbuf = (float*)alloc(262144);
    C.bars = (int*)alloc(256);
    return off;
  };

  int ti = 0;
  for (; ti < 5; ++ti){
    if (layout(tiers[ti]) <= ws_size) break;
  }
  if (ti == 5){
    // nothing fits: report ws_size in MB via output (diagnostic)
    hipLaunchKernelGGL(diag_k, dim3(1), dim3(512), 0, stream, (float*)d_out, (float)(ws_size >> 20));
    return;
  }
  Tier t = tiers[ti];
  C.tc = t.tc;
  C.lg = (t.tc == 128) ? 7 : (t.tc == 64) ? 6 : 5;

  if (t.hslo)      run_pipeline<1,1>(C, stream);
  else if (t.wlo)  run_pipeline<0,1>(C, stream);
  else             run_pipeline<0,0>(C, stream);
}

// Round 4
// 68102.203 us; speedup vs baseline: 1.0533x; 1.0533x over previous
//
#include <hip/hip_runtime.h>

// ---------------------------------------------------------------------------
// Shapes
// ---------------------------------------------------------------------------
#define B_  128
#define T_  512

typedef unsigned short u16;
typedef unsigned int   u32;
typedef __attribute__((ext_vector_type(8))) __bf16 bf16x8;
typedef __attribute__((ext_vector_type(4))) float  f32x4;

static __device__ __forceinline__ u16 f2bf(float f){
  u32 u = __float_as_uint(f);
  return (u16)((u + 0x7fffu + ((u >> 16) & 1u)) >> 16);
}
static __device__ __forceinline__ float bf2f(u16 s){ return __uint_as_float(((u32)s) << 16); }

static __device__ __forceinline__ void gll16(const void* g, void* l){
  __builtin_amdgcn_global_load_lds((const __attribute__((address_space(1))) u32*)g,
                                   (__attribute__((address_space(3))) u32*)l, 16, 0, 0);
}

// ---------------------------------------------------------------------------
// Weight prep: W[K][2048] f32 -> transposed hi/lo bf16 planes [2048][K]
// ---------------------------------------------------------------------------
__global__ __launch_bounds__(256) void wsplit(const float* __restrict__ src,
                                              u16* __restrict__ dhi, u16* __restrict__ dlo, int K){
  __shared__ float t[32][33];
  const int k0 = (int)blockIdx.x << 5, j0 = (int)blockIdx.y << 5;
  const int tx = (int)threadIdx.x & 31, ty = (int)threadIdx.x >> 5;
#pragma unroll
  for (int i = 0; i < 4; ++i){
    int k = ty + (i << 3);
    t[k][tx] = src[(size_t)(k0 + k) * 2048 + j0 + tx];
  }
  __syncthreads();
#pragma unroll
  for (int i = 0; i < 4; ++i){
    int j = ty + (i << 3);
    float v = t[tx][j];
    u16 hi = f2bf(v);
    size_t di = (size_t)(j0 + j) * K + k0 + tx;
    dhi[di] = hi;
    if (dlo) dlo[di] = f2bf(v - bf2f(hi));
  }
}

__global__ void misc_init(int* f){ f[(int)blockIdx.x * 256 + (int)threadIdx.x] = 0; }

__global__ void diag_k(float* out, float v){ if (threadIdx.x < 512) out[threadIdx.x] = v; }

// ---------------------------------------------------------------------------
// L1 input projection: xp[b][tt][c] = b1[c] + sum_f x[b][t0+tt][f] * Wx1[f][c]
// ---------------------------------------------------------------------------
__global__ __launch_bounds__(256) void xproj1(const float* __restrict__ x, const float* __restrict__ wx1,
                                              const float* __restrict__ b1, float* __restrict__ xp,
                                              int t0, int lg){
  int n = B_ << (lg + 9);
  int tcm1 = (1 << lg) - 1;
  for (int i = (int)blockIdx.x * 256 + (int)threadIdx.x; i < n; i += (int)gridDim.x * 256){
    int c4 = i & 511;
    int bt = i >> 9;
    int tt = bt & tcm1;
    int b  = bt >> lg;
    float4 xv = *(const float4*)(x + (((size_t)b * T_ + t0 + tt) << 2));
    float4 w0 = *(const float4*)(wx1 + (c4 << 2));
    float4 w1 = *(const float4*)(wx1 + 2048 + (c4 << 2));
    float4 w2 = *(const float4*)(wx1 + 4096 + (c4 << 2));
    float4 w3 = *(const float4*)(wx1 + 6144 + (c4 << 2));
    float4 bb = *(const float4*)(b1 + (c4 << 2));
    float4 o;
    o.x = bb.x + xv.x*w0.x + xv.y*w1.x + xv.z*w2.x + xv.w*w3.x;
    o.y = bb.y + xv.x*w0.y + xv.y*w1.y + xv.z*w2.y + xv.w*w3.y;
    o.z = bb.z + xv.x*w0.z + xv.y*w1.z + xv.z*w2.z + xv.w*w3.z;
    o.w = bb.w + xv.x*w0.w + xv.y*w1.w + xv.z*w2.w + xv.w*w3.w;
    *(float4*)(xp + ((size_t)bt << 11) + (c4 << 2)) = o;
  }
}

// ---------------------------------------------------------------------------
// Projection GEMM: xp rows (+)= A rows @ W + bias (unchanged from r3)
// ---------------------------------------------------------------------------
struct ProjArgs {
  const u16* ah; const u16* al;
  const u16* wh; const u16* wl;
  long wstride;
  const float* bias;
  float* xp;
  int t0, dir, accum, lg, sb;
};

template<int HSLO, int WLO>
__global__ __launch_bounds__(256, 1) void proj_gemm(ProjArgs p){
  extern __shared__ char smem[];
  const int mt = (int)blockIdx.x;
  const int nt = (int)blockIdx.y;
  const int tid = (int)threadIdx.x;
  const int w = tid >> 6, lane = tid & 63;
  const int wm = w & 1, wn = w >> 1;
  const int l15 = lane & 15, l4 = lane >> 4;
  const int tcm1 = (1 << p.lg) - 1;
  const int b0 = mt << p.sb;

  f32x4 acc[4][4];
#pragma unroll
  for (int m2 = 0; m2 < 4; ++m2)
#pragma unroll
    for (int n2 = 0; n2 < 4; ++n2) acc[m2][n2] = (f32x4){0.f,0.f,0.f,0.f};

  const u16* gsrc = nullptr;
  if (w == 0) gsrc = p.ah;
  else if (w == 1) { if constexpr (HSLO) gsrc = p.al; }
  else if (w == 2) gsrc = p.wh;
  else { if constexpr (WLO) gsrc = p.wl; }

  auto do_stage = [&](int ks, int buf){
    if (!gsrc) return;
    char* base = smem + (buf << 16) + (w << 14);
#pragma unroll
    for (int ii = 0; ii < 16; ++ii){
      int r = (ii << 3) + (lane >> 3);
      int co = ((lane & 7) << 4) ^ ((r & 7) << 4);
      size_t rowoff;
      if (w < 2){
        int grow = (b0 + (r >> p.lg)) * T_ + p.t0 + p.dir * (r & tcm1);
        rowoff = ((size_t)grow) << 10;
      } else {
        rowoff = ((size_t)((nt << 7) + r)) * ((size_t)p.wstride << 1);
      }
      gll16((const char*)gsrc + rowoff + (ks << 7) + co, base + (ii << 10));
    }
  };

  do_stage(0, 0);
  for (int ks = 0; ks < 8; ++ks){
    __syncthreads();
    if (ks < 7) do_stage(ks + 1, (ks + 1) & 1);
    const char* bb = smem + ((ks & 1) << 16);
    const char* Ah = bb;
    const char* Al = bb + 16384;
    const char* Wh = bb + 32768;
    const char* Wl = bb + 49152;
#pragma unroll
    for (int kk = 0; kk < 2; ++kk){
      bf16x8 ahf[4], alf[4];
#pragma unroll
      for (int m2 = 0; m2 < 4; ++m2){
        int r = (wm << 6) + (m2 << 4) + l15;
        int off = (r << 7) + (((kk << 6) + (l4 << 4)) ^ ((r & 7) << 4));
        ahf[m2] = *(const bf16x8*)(Ah + off);
        if constexpr (HSLO) alf[m2] = *(const bf16x8*)(Al + off);
      }
#pragma unroll
      for (int n2 = 0; n2 < 4; ++n2){
        int col = (wn << 6) + (n2 << 4) + l15;
        int off = (col << 7) + (((kk << 6) + (l4 << 4)) ^ ((col & 7) << 4));
        bf16x8 bh = *(const bf16x8*)(Wh + off);
        bf16x8 bl;
        if constexpr (WLO) bl = *(const bf16x8*)(Wl + off);
#pragma unroll
        for (int m2 = 0; m2 < 4; ++m2){
          acc[m2][n2] = __builtin_amdgcn_mfma_f32_16x16x32_bf16(ahf[m2], bh, acc[m2][n2], 0,0,0);
          if constexpr (WLO)
            acc[m2][n2] = __builtin_amdgcn_mfma_f32_16x16x32_bf16(ahf[m2], bl, acc[m2][n2], 0,0,0);
          if constexpr (HSLO)
            acc[m2][n2] = __builtin_amdgcn_mfma_f32_16x16x32_bf16(alf[m2], bh, acc[m2][n2], 0,0,0);
        }
      }
    }
  }
#pragma unroll
  for (int n2 = 0; n2 < 4; ++n2){
    int gcol = (nt << 7) + (wn << 6) + (n2 << 4) + l15;
    float bs = p.bias ? p.bias[gcol] : 0.f;
#pragma unroll
    for (int m2 = 0; m2 < 4; ++m2){
#pragma unroll
      for (int i = 0; i < 4; ++i){
        int r = (wm << 6) + (m2 << 4) + (l4 << 2) + i;
        size_t idx = (((size_t)(mt << 7) + r) << 11) + gcol;
        float v = acc[m2][n2][i] + bs;
        if (p.accum) v += p.xp[idx];
        p.xp[idx] = v;
      }
    }
  }
}

// ---------------------------------------------------------------------------
// Persistent LSTM scan v2: 8 bgs(16 rows) x 32 WGs(16 units), 512 thr/WG.
// bg = blockIdx%8 (XCD-local under round-robin). Flag-array barrier.
// LDS: Wh hi[/lo] [64c][512K] (64/128 KB, once) + h-hi stage 16 KB + zb 8 KB.
// h-lo A-fragments read per-lane directly from global (L2-local).
// ---------------------------------------------------------------------------
struct ScanArgs {
  const u16* wh_hi; const u16* wh_lo;
  const float* xp;
  u16* hs_hi; u16* hs_lo;
  u16* hc_hi; u16* hc_lo;     // [2][B][512] exchange (always hi+lo)
  float* cbuf;
  int* flags;                 // [8][32] slots, 32 ints (128 B) apart
  int t0, dir, nsteps, first, ep0, lg;
};

template<int HSLO, int WLO>
__global__ __launch_bounds__(512, 1) void lstm_scan(ScanArgs a){
  extern __shared__ char smem[];
  char* whh = smem;
  char* whl = smem + 65536;
  char* ahi = smem + (WLO ? 131072 : 65536);
  float* zb  = (float*)(ahi + 16384);   // [2][16][64] f32

  const int bid = (int)blockIdx.x;
  const int bg = bid & 7, wg = bid >> 3;
  const int b0 = bg << 4, u0 = wg << 4;
  const int tid = (int)threadIdx.x;
  const int w = tid >> 6, lane = tid & 63;
  const int ct = w >> 1, kh = w & 1;
  const int l15 = lane & 15, l4 = lane >> 4;
  int* fl_my = a.flags + (bg << 10) + (wg << 5);

  // stage Wh slice once: local col c in [0,64), global col (c>>4)*512 + u0 + (c&15)
#pragma unroll
  for (int i = 0; i < 8; ++i){
    int c = (w << 3) + i;
    int gc = ((c >> 4) << 9) + u0 + (c & 15);
    int co = (lane << 4) ^ ((c & 7) << 4);
    gll16((const char*)a.wh_hi + ((size_t)gc << 10) + co, whh + (c << 10));
    if constexpr (WLO)
      gll16((const char*)a.wh_lo + ((size_t)gc << 10) + co, whl + (c << 10));
  }

  const int row = (tid >> 4) & 15, uu = tid & 15;   // gate threads: tid<256
  int ep = a.ep0;
  float c_reg = 0.f;

  auto barrier = [&](int target){
    __syncthreads();
    if (tid == 0)
      __hip_atomic_store(fl_my, target, __ATOMIC_RELEASE, __HIP_MEMORY_SCOPE_AGENT);
    if (w == 0){
      const int* f = a.flags + (bg << 10) + ((lane & 31) << 5);
      while (1){
        int v = __hip_atomic_load(f, __ATOMIC_RELAXED, __HIP_MEMORY_SCOPE_AGENT);
        if (__all(v >= target)) break;
        __builtin_amdgcn_s_sleep(1);
      }
    }
    __syncthreads();
    (void)__hip_atomic_load(fl_my, __ATOMIC_ACQUIRE, __HIP_MEMORY_SCOPE_AGENT); // L1 inval per wave
  };

  if (a.first){
    if (tid < 256){
      int pz = a.t0 & 1;
      size_t ci = ((size_t)pz << 16) + ((size_t)(b0 + row) << 9) + u0 + uu;
      a.hc_hi[ci] = 0; a.hc_lo[ci] = 0;
    }
    barrier(++ep);
  } else if (tid < 256){
    c_reg = a.cbuf[((size_t)(b0 + row) << 9) + u0 + uu];
  }

  for (int tt = 0; tt < a.nsteps; ++tt){
    int gt = a.t0 + a.dir * tt;
    int par = gt & 1, pn = par ^ 1;

    // xg prefetch
    float xg0 = 0.f, xg1 = 0.f, xg2 = 0.f, xg3 = 0.f;
    if (tid < 256){
      const float* xr = a.xp + (((size_t)(((b0 + row) << a.lg) + tt)) << 11) + u0 + uu;
      xg0 = xr[0]; xg1 = xr[512]; xg2 = xr[1024]; xg3 = xr[1536];
    }

    // h-lo A-fragments, per-lane direct global loads (my K-half)
    const u16* hlo = a.hc_lo + ((size_t)par << 16) + ((size_t)(b0 + l15) << 9);
    bf16x8 alo[8];
#pragma unroll
    for (int j = 0; j < 8; ++j){
      int ks = (kh << 3) + j;
      alo[j] = *(const bf16x8*)(hlo + (ks << 5) + (l4 << 3));
    }

    // stage h-hi rows (wave w: rows 2w, 2w+1), pre-swizzled source
#pragma unroll
    for (int i = 0; i < 2; ++i){
      int r = (w << 1) + i;
      int co = (lane << 4) ^ ((r & 7) << 4);
      gll16((const char*)a.hc_hi + ((size_t)par << 17) + ((size_t)(b0 + r) << 10) + co,
            ahi + (r << 10));
    }
    __syncthreads();

    // z partial: wave (ct,kh) computes 16 rows x 16 cols over K-half
    f32x4 acc0 = (f32x4){0.f,0.f,0.f,0.f};
    f32x4 acc1 = (f32x4){0.f,0.f,0.f,0.f};
    const int c = (ct << 4) + l15;
    const int cswz = (c & 7) << 4;
    const int aswz = (l15 & 7) << 4;
#pragma unroll
    for (int j = 0; j < 8; ++j){
      int ks = (kh << 3) + j;
      int ko = (ks << 6) + (l4 << 4);
      bf16x8 ah = *(const bf16x8*)(ahi + (l15 << 10) + (ko ^ aswz));
      bf16x8 bh = *(const bf16x8*)(whh + (c << 10) + (ko ^ cswz));
      acc0 = __builtin_amdgcn_mfma_f32_16x16x32_bf16(ah, bh, acc0, 0,0,0);
      if constexpr (WLO){
        bf16x8 bl = *(const bf16x8*)(whl + (c << 10) + (ko ^ cswz));
        acc0 = __builtin_amdgcn_mfma_f32_16x16x32_bf16(ah, bl, acc0, 0,0,0);
      }
      acc1 = __builtin_amdgcn_mfma_f32_16x16x32_bf16(alo[j], bh, acc1, 0,0,0);
    }
    acc0[0] += acc1[0]; acc0[1] += acc1[1]; acc0[2] += acc1[2]; acc0[3] += acc1[3];
#pragma unroll
    for (int i = 0; i < 4; ++i)
      zb[(kh << 10) + (((l4 << 2) + i) << 6) + c] = acc0[i];
    __syncthreads();

    if (tid < 256){
      int zo_ = (row << 6) + uu;
      float zi = zb[zo_]      + zb[1024 + zo_]      + xg0;
      float zf = zb[zo_ + 16] + zb[1024 + zo_ + 16] + xg1;
      float zg = zb[zo_ + 32] + zb[1024 + zo_ + 32] + xg2;
      float zo = zb[zo_ + 48] + zb[1024 + zo_ + 48] + xg3;
      float ig = 1.f / (1.f + expf(-zi));
      float fg = 1.f / (1.f + expf(-zf));
      float gg = tanhf(zg);
      float og = 1.f / (1.f + expf(-zo));
      c_reg = fg * c_reg + ig * gg;
      float h = og * tanhf(c_reg);
      u16 hh = f2bf(h);
      u16 hl = f2bf(h - bf2f(hh));
      size_t ci = ((size_t)pn << 16) + ((size_t)(b0 + row) << 9) + u0 + uu;
      a.hc_hi[ci] = hh; a.hc_lo[ci] = hl;
      size_t si = (((size_t)(b0 + row) * T_ + gt) << 9) + u0 + uu;
      a.hs_hi[si] = hh;
      if constexpr (HSLO) a.hs_lo[si] = hl;
    }
    barrier(++ep);
  }
  if (tid < 256) a.cbuf[((size_t)(b0 + row) << 9) + u0 + uu] = c_reg;
}

// ---------------------------------------------------------------------------
// Final dense head
// ---------------------------------------------------------------------------
template<int HSLO>
__global__ __launch_bounds__(512) void dense_k(const u16* __restrict__ hhi, const u16* __restrict__ hlo,
                                               const float* __restrict__ wd, const float* __restrict__ bd,
                                               float* __restrict__ out){
  int tid = (int)threadIdx.x;
  int b = tid >> 2, o = tid & 3;
  const u16* ph = hhi + (((size_t)b * T_ + (T_ - 1)) << 9);
  const u16* pl = hlo + (((size_t)b * T_ + (T_ - 1)) << 9);
  float s = 0.f;
  for (int u = 0; u < 512; ++u){
    float h = bf2f(ph[u]);
    if constexpr (HSLO) h += bf2f(pl[u]);
    s += h * wd[(u << 2) + o];
  }
  out[(b << 2) + o] = s + bd[o];
}

// ---------------------------------------------------------------------------
// Host
// ---------------------------------------------------------------------------
struct HostCtx {
  const float* x; const float* wx1; const float* b1;
  const float* srcW[8];
  const float* Wx4;
  const float* b2; const float* bf3; const float* bb3; const float* b4;
  const float* Wd; const float* bd;
  u16* wth[8]; u16* wtl[8];
  u16* wx4h; u16* wx4l;
  float* xp;
  u16 *PAh, *PAl, *PBh, *PBl, *hch, *hcl;
  float* cbuf; int* flags;
  float* out;
  int tc, lg;
};

template<int HSLO, int WLO>
static void run_pipeline(const HostCtx& C, hipStream_t stream){
  const u32 scan_lds = WLO ? 155648u : 90112u;
  hipFuncSetAttribute((const void*)&lstm_scan<HSLO,WLO>, hipFuncAttributeMaxDynamicSharedMemorySize, (int)scan_lds);
  hipFuncSetAttribute((const void*)&proj_gemm<HSLO,WLO>, hipFuncAttributeMaxDynamicSharedMemorySize, 131072);

  for (int i = 0; i < 8; ++i)
    hipLaunchKernelGGL(wsplit, dim3(16, 64), dim3(256), 0, stream, C.srcW[i], C.wth[i], WLO ? C.wtl[i] : nullptr, 512);
  hipLaunchKernelGGL(wsplit, dim3(32, 64), dim3(256), 0, stream, C.Wx4, C.wx4h, WLO ? C.wx4l : nullptr, 1024);
  hipLaunchKernelGGL(misc_init, dim3(32), dim3(256), 0, stream, C.flags);

  const int tc = C.tc, lg = C.lg, NC = 512 / tc, sb = 7 - lg;
  int ep = 0;

  auto scan = [&](int wi, u16* hsh_, u16* hsl_, int t0, int dir, int first){
    ScanArgs sa;
    sa.wh_hi = C.wth[wi]; sa.wh_lo = C.wtl[wi]; sa.xp = C.xp;
    sa.hs_hi = hsh_; sa.hs_lo = hsl_; sa.hc_hi = C.hch; sa.hc_lo = C.hcl;
    sa.cbuf = C.cbuf; sa.flags = C.flags;
    sa.t0 = t0; sa.dir = dir; sa.nsteps = tc; sa.first = first; sa.ep0 = ep; sa.lg = lg;
    void* args[] = { &sa };
    hipLaunchCooperativeKernel((const void*)&lstm_scan<HSLO,WLO>, dim3(256), dim3(512), args, scan_lds, stream);
    ep += tc + (first ? 1 : 0);
  };
  auto proj = [&](const u16* ah_, const u16* al_, const u16* wh_, const u16* wl_, long wstr,
                  const float* bias_, int t0, int dir, int accum){
    ProjArgs pa;
    pa.ah = ah_; pa.al = al_; pa.wh = wh_; pa.wl = wl_; pa.wstride = wstr;
    pa.bias = bias_; pa.xp = C.xp; pa.t0 = t0; pa.dir = dir; pa.accum = accum; pa.lg = lg; pa.sb = sb;
    hipLaunchKernelGGL(HIP_KERNEL_NAME(proj_gemm<HSLO,WLO>), dim3(tc, 16), dim3(256), 131072, stream, pa);
  };

  // L1
  for (int c = 0; c < NC; ++c){
    hipLaunchKernelGGL(xproj1, dim3(1024), dim3(256), 0, stream, C.x, C.wx1, C.b1, C.xp, c * tc, lg);
    scan(0, C.PAh, C.PAl, c * tc, 1, c == 0);
  }
  // L2
  for (int c = 0; c < NC; ++c){
    proj(C.PAh, C.PAl, C.wth[1], C.wtl[1], 512, C.b2, c * tc, 1, 0);
    scan(2, C.PAh, C.PAl, c * tc, 1, c == 0);
  }
  // L3 forward
  for (int c = 0; c < NC; ++c){
    proj(C.PAh, C.PAl, C.wth[3], C.wtl[3], 512, C.bf3, c * tc, 1, 0);
    scan(4, C.PBh, C.PBl, c * tc, 1, c == 0);
  }
  // L3 backward
  for (int c = 0; c < NC; ++c){
    int t0 = 511 - c * tc;
    proj(C.PAh, C.PAl, C.wth[5], C.wtl[5], 512, C.bb3, t0, -1, 0);
    scan(6, C.PAh, C.PAl, t0, -1, c == 0);
  }
  // L4
  for (int c = 0; c < NC; ++c){
    proj(C.PBh, C.PBl, C.wx4h, C.wx4l, 1024, C.b4, c * tc, 1, 0);
    proj(C.PAh, C.PAl, C.wx4h + 512, WLO ? (C.wx4l + 512) : nullptr, 1024, nullptr, c * tc, 1, 1);
    scan(7, C.PBh, C.PBl, c * tc, 1, c == 0);
  }
  hipLaunchKernelGGL(HIP_KERNEL_NAME(dense_k<HSLO>), dim3(1), dim3(512), 0, stream, C.PBh, C.PBl, C.Wd, C.bd, C.out);
}

extern "C" void kernel_launch(void* const* d_in, const int* in_sizes, int n_in,
                              void* d_out, int out_size, void* d_ws, size_t ws_size,
                              hipStream_t stream){
  (void)in_sizes; (void)n_in; (void)out_size;
  HostCtx C;
  C.x   = (const float*)d_in[0];
  C.wx1 = (const float*)d_in[1];
  C.b1  = (const float*)d_in[3];
  C.srcW[0] = (const float*)d_in[2];   // Wh1
  C.srcW[1] = (const float*)d_in[4];   // Wx2
  C.srcW[2] = (const float*)d_in[5];   // Wh2
  C.srcW[3] = (const float*)d_in[7];   // Wxf3
  C.srcW[4] = (const float*)d_in[8];   // Whf3
  C.srcW[5] = (const float*)d_in[10];  // Wxb3
  C.srcW[6] = (const float*)d_in[11];  // Whb3
  C.srcW[7] = (const float*)d_in[14];  // Wh4
  C.b2  = (const float*)d_in[6];
  C.bf3 = (const float*)d_in[9];
  C.bb3 = (const float*)d_in[12];
  C.Wx4 = (const float*)d_in[13];
  C.b4  = (const float*)d_in[15];
  C.Wd  = (const float*)d_in[16];
  C.bd  = (const float*)d_in[17];
  C.out = (float*)d_out;

  struct Tier { int tc, hslo, wlo; };
  const Tier tiers[5] = { {128,1,1}, {64,1,1}, {64,0,1}, {32,0,1}, {32,0,0} };

  auto layout = [&](Tier t)->size_t{
    size_t off = 0;
    auto alloc = [&](size_t sz)->char*{
      char* pp = (char*)d_ws + off; off += sz; off = (off + 255) & ~(size_t)255; return pp;
    };
    for (int i = 0; i < 8; ++i){
      C.wth[i] = (u16*)alloc(2097152);
      C.wtl[i] = t.wlo ? (u16*)alloc(2097152) : nullptr;
    }
    C.wx4h = (u16*)alloc(4194304);
    C.wx4l = t.wlo ? (u16*)alloc(4194304) : nullptr;
    C.xp = (float*)alloc((size_t)B_ * t.tc * 2048 * 4);
    C.PAh = (u16*)alloc(67108864);
    C.PAl = t.hslo ? (u16*)alloc(67108864) : nullptr;
    C.PBh = (u16*)alloc(67108864);
    C.PBl = t.hslo ? (u16*)alloc(67108864) : nullptr;
    C.hch = (u16*)alloc(262144);
    C.hcl = (u16*)alloc(262144);
    C.cbuf = (float*)alloc(262144);
    C.flags = (int*)alloc(32768);
    return off;
  };

  int ti = 0;
  for (; ti < 5; ++ti){
    if (layout(tiers[ti]) <= ws_size) break;
  }
  if (ti == 5){
    hipLaunchKernelGGL(diag_k, dim3(1), dim3(512), 0, stream, (float*)d_out, (float)(ws_size >> 20));
    return;
  }
  Tier t = tiers[ti];
  C.tc = t.tc;
  C.lg = (t.tc == 128) ? 7 : (t.tc == 64) ? 6 : 5;

  if (t.hslo)      run_pipeline<1,1>(C, stream);
  else if (t.wlo)  run_pipeline<0,1>(C, stream);
  else             run_pipeline<0,0>(C, stream);
}

// Round 5
// 19283.705 us; speedup vs baseline: 3.7198x; 3.5316x over previous
//
#include <hip/hip_runtime.h>

// ---------------------------------------------------------------------------
// Shapes
// ---------------------------------------------------------------------------
#define B_  128
#define T_  512

typedef unsigned short u16;
typedef unsigned int   u32;
typedef __attribute__((ext_vector_type(8))) __bf16 bf16x8;
typedef __attribute__((ext_vector_type(4))) float  f32x4;

static __device__ __forceinline__ u16 f2bf(float f){
  u32 u = __float_as_uint(f);
  return (u16)((u + 0x7fffu + ((u >> 16) & 1u)) >> 16);
}
static __device__ __forceinline__ float bf2f(u16 s){ return __uint_as_float(((u32)s) << 16); }

static __device__ __forceinline__ void gll16(const void* g, void* l){
  __builtin_amdgcn_global_load_lds((const __attribute__((address_space(1))) u32*)g,
                                   (__attribute__((address_space(3))) u32*)l, 16, 0, 0);
}

// LLC-coherent (cache-bypassing) 16B load with immediate offset
template<int OFF>
static __device__ __forceinline__ bf16x8 ld16sc(const char* p){
  bf16x8 r;
  asm volatile("global_load_dwordx4 %0, %1, off offset:%2 sc0 sc1"
               : "=v"(r) : "v"(p), "i"(OFF));
  return r;
}
// LLC-coherent 2B store
static __device__ __forceinline__ void st16sc(char* p, u32 v){
  asm volatile("global_store_short %0, %1, off sc0 sc1" :: "v"(p), "v"(v) : "memory");
}

// ---------------------------------------------------------------------------
// Weight prep: W[K][2048] f32 -> transposed hi/lo bf16 planes [2048][K]
// ---------------------------------------------------------------------------
__global__ __launch_bounds__(256) void wsplit(const float* __restrict__ src,
                                              u16* __restrict__ dhi, u16* __restrict__ dlo, int K){
  __shared__ float t[32][33];
  const int k0 = (int)blockIdx.x << 5, j0 = (int)blockIdx.y << 5;
  const int tx = (int)threadIdx.x & 31, ty = (int)threadIdx.x >> 5;
#pragma unroll
  for (int i = 0; i < 4; ++i){
    int k = ty + (i << 3);
    t[k][tx] = src[(size_t)(k0 + k) * 2048 + j0 + tx];
  }
  __syncthreads();
#pragma unroll
  for (int i = 0; i < 4; ++i){
    int j = ty + (i << 3);
    float v = t[tx][j];
    u16 hi = f2bf(v);
    size_t di = (size_t)(j0 + j) * K + k0 + tx;
    dhi[di] = hi;
    if (dlo) dlo[di] = f2bf(v - bf2f(hi));
  }
}

__global__ void misc_init(int* f){
  __hip_atomic_store(f + (int)blockIdx.x * 256 + (int)threadIdx.x, 0,
                     __ATOMIC_RELAXED, __HIP_MEMORY_SCOPE_AGENT);
}

__global__ void diag_k(float* out, float v){ if (threadIdx.x < 512) out[threadIdx.x] = v; }

// ---------------------------------------------------------------------------
// L1 input projection (memory-bound, tiny F=4)
// ---------------------------------------------------------------------------
__global__ __launch_bounds__(256) void xproj1(const float* __restrict__ x, const float* __restrict__ wx1,
                                              const float* __restrict__ b1, float* __restrict__ xp,
                                              int t0, int lg){
  int n = B_ << (lg + 9);
  int tcm1 = (1 << lg) - 1;
  for (int i = (int)blockIdx.x * 256 + (int)threadIdx.x; i < n; i += (int)gridDim.x * 256){
    int c4 = i & 511;
    int bt = i >> 9;
    int tt = bt & tcm1;
    int b  = bt >> lg;
    float4 xv = *(const float4*)(x + (((size_t)b * T_ + t0 + tt) << 2));
    float4 w0 = *(const float4*)(wx1 + (c4 << 2));
    float4 w1 = *(const float4*)(wx1 + 2048 + (c4 << 2));
    float4 w2 = *(const float4*)(wx1 + 4096 + (c4 << 2));
    float4 w3 = *(const float4*)(wx1 + 6144 + (c4 << 2));
    float4 bb = *(const float4*)(b1 + (c4 << 2));
    float4 o;
    o.x = bb.x + xv.x*w0.x + xv.y*w1.x + xv.z*w2.x + xv.w*w3.x;
    o.y = bb.y + xv.x*w0.y + xv.y*w1.y + xv.z*w2.y + xv.w*w3.y;
    o.z = bb.z + xv.x*w0.z + xv.y*w1.z + xv.z*w2.z + xv.w*w3.z;
    o.w = bb.w + xv.x*w0.w + xv.y*w1.w + xv.z*w2.w + xv.w*w3.w;
    *(float4*)(xp + ((size_t)bt << 11) + (c4 << 2)) = o;
  }
}

// ---------------------------------------------------------------------------
// Projection GEMM (unchanged from r4)
// ---------------------------------------------------------------------------
struct ProjArgs {
  const u16* ah; const u16* al;
  const u16* wh; const u16* wl;
  long wstride;
  const float* bias;
  float* xp;
  int t0, dir, accum, lg, sb;
};

template<int HSLO, int WLO>
__global__ __launch_bounds__(256, 1) void proj_gemm(ProjArgs p){
  extern __shared__ char smem[];
  const int mt = (int)blockIdx.x;
  const int nt = (int)blockIdx.y;
  const int tid = (int)threadIdx.x;
  const int w = tid >> 6, lane = tid & 63;
  const int wm = w & 1, wn = w >> 1;
  const int l15 = lane & 15, l4 = lane >> 4;
  const int tcm1 = (1 << p.lg) - 1;
  const int b0 = mt << p.sb;

  f32x4 acc[4][4];
#pragma unroll
  for (int m2 = 0; m2 < 4; ++m2)
#pragma unroll
    for (int n2 = 0; n2 < 4; ++n2) acc[m2][n2] = (f32x4){0.f,0.f,0.f,0.f};

  const u16* gsrc = nullptr;
  if (w == 0) gsrc = p.ah;
  else if (w == 1) { if constexpr (HSLO) gsrc = p.al; }
  else if (w == 2) gsrc = p.wh;
  else { if constexpr (WLO) gsrc = p.wl; }

  auto do_stage = [&](int ks, int buf){
    if (!gsrc) return;
    char* base = smem + (buf << 16) + (w << 14);
#pragma unroll
    for (int ii = 0; ii < 16; ++ii){
      int r = (ii << 3) + (lane >> 3);
      int co = ((lane & 7) << 4) ^ ((r & 7) << 4);
      size_t rowoff;
      if (w < 2){
        int grow = (b0 + (r >> p.lg)) * T_ + p.t0 + p.dir * (r & tcm1);
        rowoff = ((size_t)grow) << 10;
      } else {
        rowoff = ((size_t)((nt << 7) + r)) * ((size_t)p.wstride << 1);
      }
      gll16((const char*)gsrc + rowoff + (ks << 7) + co, base + (ii << 10));
    }
  };

  do_stage(0, 0);
  for (int ks = 0; ks < 8; ++ks){
    __syncthreads();
    if (ks < 7) do_stage(ks + 1, (ks + 1) & 1);
    const char* bb = smem + ((ks & 1) << 16);
    const char* Ah = bb;
    const char* Al = bb + 16384;
    const char* Wh = bb + 32768;
    const char* Wl = bb + 49152;
#pragma unroll
    for (int kk = 0; kk < 2; ++kk){
      bf16x8 ahf[4], alf[4];
#pragma unroll
      for (int m2 = 0; m2 < 4; ++m2){
        int r = (wm << 6) + (m2 << 4) + l15;
        int off = (r << 7) + (((kk << 6) + (l4 << 4)) ^ ((r & 7) << 4));
        ahf[m2] = *(const bf16x8*)(Ah + off);
        if constexpr (HSLO) alf[m2] = *(const bf16x8*)(Al + off);
      }
#pragma unroll
      for (int n2 = 0; n2 < 4; ++n2){
        int col = (wn << 6) + (n2 << 4) + l15;
        int off = (col << 7) + (((kk << 6) + (l4 << 4)) ^ ((col & 7) << 4));
        bf16x8 bh = *(const bf16x8*)(Wh + off);
        bf16x8 bl;
        if constexpr (WLO) bl = *(const bf16x8*)(Wl + off);
#pragma unroll
        for (int m2 = 0; m2 < 4; ++m2){
          acc[m2][n2] = __builtin_amdgcn_mfma_f32_16x16x32_bf16(ahf[m2], bh, acc[m2][n2], 0,0,0);
          if constexpr (WLO)
            acc[m2][n2] = __builtin_amdgcn_mfma_f32_16x16x32_bf16(ahf[m2], bl, acc[m2][n2], 0,0,0);
          if constexpr (HSLO)
            acc[m2][n2] = __builtin_amdgcn_mfma_f32_16x16x32_bf16(alf[m2], bh, acc[m2][n2], 0,0,0);
        }
      }
    }
  }
#pragma unroll
  for (int n2 = 0; n2 < 4; ++n2){
    int gcol = (nt << 7) + (wn << 6) + (n2 << 4) + l15;
    float bs = p.bias ? p.bias[gcol] : 0.f;
#pragma unroll
    for (int m2 = 0; m2 < 4; ++m2){
#pragma unroll
      for (int i = 0; i < 4; ++i){
        int r = (wm << 6) + (m2 << 4) + (l4 << 2) + i;
        size_t idx = (((size_t)(mt << 7) + r) << 11) + gcol;
        float v = acc[m2][n2][i] + bs;
        if (p.accum) v += p.xp[idx];
        p.xp[idx] = v;
      }
    }
  }
}

// ---------------------------------------------------------------------------
// Persistent LSTM scan v3: fence-free LLC exchange.
// 8 bgs(16 rows) x 32 WGs(16 units), 512 thr/WG, 1 WG/CU.
// hc layout: [par][b][plane(hi,lo)][512] u16  (par stride 1<<18 bytes)
// No release/acquire anywhere in the loop: h via sc0sc1 stores/loads,
// ordering via s_waitcnt vmcnt(0) + relaxed flag; A-frags loaded straight
// from LLC into MFMA operands (no LDS h staging).
// ---------------------------------------------------------------------------
struct ScanArgs {
  const u16* wh_hi; const u16* wh_lo;
  const float* xp;
  u16* hs_hi; u16* hs_lo;
  u16* hc;                    // [2][B][2][512]
  float* cbuf;
  int* flags;                 // [8][32] slots, 128B apart
  int t0, dir, nsteps, first, ep0, lg;
};

template<int HSLO, int WLO>
__global__ __launch_bounds__(512, 1) void lstm_scan(ScanArgs a){
  extern __shared__ char smem[];
  char* whh = smem;
  char* whl = smem + 65536;
  float* zb = (float*)(smem + (WLO ? 131072 : 65536));   // [2][16][64]

  const int bid = (int)blockIdx.x;
  const int bg = bid & 7, wg = bid >> 3;
  const int b0 = bg << 4, u0 = wg << 4;
  const int tid = (int)threadIdx.x;
  const int w = tid >> 6, lane = tid & 63;
  const int ct = w >> 1, kh = w & 1;
  const int l15 = lane & 15, l4 = lane >> 4;
  int* fl_my = a.flags + (bg << 10) + (wg << 5);
  char* hc8 = (char*)a.hc;

  // stage Wh slice once (local col c -> global col (c/16)*512 + u0 + c%16)
#pragma unroll
  for (int i = 0; i < 8; ++i){
    int c = (w << 3) + i;
    int gc = ((c >> 4) << 9) + u0 + (c & 15);
    int co = (lane << 4) ^ ((c & 7) << 4);
    gll16((const char*)a.wh_hi + ((size_t)gc << 10) + co, whh + (c << 10));
    if constexpr (WLO)
      gll16((const char*)a.wh_lo + ((size_t)gc << 10) + co, whl + (c << 10));
  }
  asm volatile("s_waitcnt vmcnt(0)" ::: "memory");
  __syncthreads();   // Wh visible to all waves

  const int row = (tid >> 4) & 15, uu = tid & 15;
  const int gu = u0 + uu;
  int ep = a.ep0;
  float c_reg = 0.f;

  auto barrier = [&](int target){
    __syncthreads();
    if (tid == 0)
      __hip_atomic_store(fl_my, target, __ATOMIC_RELAXED, __HIP_MEMORY_SCOPE_AGENT);
    if (w == 0){
      const int* f = a.flags + (bg << 10) + ((lane & 31) << 5);
      while (1){
        int v = __hip_atomic_load(f, __ATOMIC_RELAXED, __HIP_MEMORY_SCOPE_AGENT);
        if (__all(v >= target)) break;
        __builtin_amdgcn_s_sleep(1);
      }
    }
    __syncthreads();
  };

  if (a.first){
    if (tid < 256){
      int pz = a.t0 & 1;
      char* wb = hc8 + ((size_t)pz << 18) + ((size_t)(b0 + row) << 11) + ((size_t)gu << 1);
      st16sc(wb, 0);
      st16sc(wb + 1024, 0);
    }
    asm volatile("s_waitcnt vmcnt(0)" ::: "memory");
    barrier(++ep);
  } else if (tid < 256){
    c_reg = a.cbuf[((size_t)(b0 + row) << 9) + gu];
  }

  // per-lane fragment base (within a parity buffer)
  const size_t frag_off = ((size_t)(b0 + l15) << 11) + (kh << 9) + (l4 << 4);
  const int c = (ct << 4) + l15;
  const int cswz = (c & 7) << 4;

  for (int tt = 0; tt < a.nsteps; ++tt){
    int gt = a.t0 + a.dir * tt;
    int par = gt & 1, pn = par ^ 1;

    // gate-input prefetch (plain loads)
    float xg0 = 0.f, xg1 = 0.f, xg2 = 0.f, xg3 = 0.f;
    if (tid < 256){
      const float* xr = a.xp + (((size_t)(((b0 + row) << a.lg) + tt)) << 11) + gu;
      xg0 = xr[0]; xg1 = xr[512]; xg2 = xr[1024]; xg3 = xr[1536];
    }

    // A-fragments straight from LLC (hi + lo), sc0 sc1
    const char* fb = hc8 + ((size_t)par << 18) + frag_off;
    bf16x8 fh[8] = { ld16sc<   0>(fb), ld16sc<  64>(fb), ld16sc< 128>(fb), ld16sc< 192>(fb),
                     ld16sc< 256>(fb), ld16sc< 320>(fb), ld16sc< 384>(fb), ld16sc< 448>(fb) };
    bf16x8 fL[8] = { ld16sc<1024>(fb), ld16sc<1088>(fb), ld16sc<1152>(fb), ld16sc<1216>(fb),
                     ld16sc<1280>(fb), ld16sc<1344>(fb), ld16sc<1408>(fb), ld16sc<1472>(fb) };
    asm volatile("s_waitcnt vmcnt(0)" ::: "memory");
    __builtin_amdgcn_sched_barrier(0);

    f32x4 acc0 = (f32x4){0.f,0.f,0.f,0.f};
    f32x4 acc1 = (f32x4){0.f,0.f,0.f,0.f};
#pragma unroll
    for (int j = 0; j < 8; ++j){
      int ko = ((((kh << 3) + j) << 6) + (l4 << 4));
      bf16x8 bh = *(const bf16x8*)(whh + (c << 10) + (ko ^ cswz));
      acc0 = __builtin_amdgcn_mfma_f32_16x16x32_bf16(fh[j], bh, acc0, 0,0,0);
      if constexpr (WLO){
        bf16x8 bl = *(const bf16x8*)(whl + (c << 10) + (ko ^ cswz));
        acc0 = __builtin_amdgcn_mfma_f32_16x16x32_bf16(fh[j], bl, acc0, 0,0,0);
      }
      acc1 = __builtin_amdgcn_mfma_f32_16x16x32_bf16(fL[j], bh, acc1, 0,0,0);
    }
    acc0[0] += acc1[0]; acc0[1] += acc1[1]; acc0[2] += acc1[2]; acc0[3] += acc1[3];
#pragma unroll
    for (int i = 0; i < 4; ++i)
      zb[(kh << 10) + (((l4 << 2) + i) << 6) + c] = acc0[i];
    __syncthreads();

    if (tid < 256){
      int zo_ = (row << 6) + uu;
      float zi = zb[zo_]      + zb[1024 + zo_]      + xg0;
      float zf = zb[zo_ + 16] + zb[1024 + zo_ + 16] + xg1;
      float zg = zb[zo_ + 32] + zb[1024 + zo_ + 32] + xg2;
      float zo = zb[zo_ + 48] + zb[1024 + zo_ + 48] + xg3;
      float ig = 1.f / (1.f + expf(-zi));
      float fg = 1.f / (1.f + expf(-zf));
      float gg = tanhf(zg);
      float og = 1.f / (1.f + expf(-zo));
      c_reg = fg * c_reg + ig * gg;
      float h = og * tanhf(c_reg);
      u16 hh = f2bf(h);
      u16 hl = f2bf(h - bf2f(hh));
      char* wb = hc8 + ((size_t)pn << 18) + ((size_t)(b0 + row) << 11) + ((size_t)gu << 1);
      st16sc(wb, (u32)hh);
      st16sc(wb + 1024, (u32)hl);
      size_t si = (((size_t)(b0 + row) * T_ + gt) << 9) + gu;
      a.hs_hi[si] = hh;
      if constexpr (HSLO) a.hs_lo[si] = hl;
    }
    asm volatile("s_waitcnt vmcnt(0)" ::: "memory");   // h at LLC before flag
    barrier(++ep);
  }
  if (tid < 256) a.cbuf[((size_t)(b0 + row) << 9) + gu] = c_reg;
}

// ---------------------------------------------------------------------------
// Final dense head
// ---------------------------------------------------------------------------
template<int HSLO>
__global__ __launch_bounds__(512) void dense_k(const u16* __restrict__ hhi, const u16* __restrict__ hlo,
                                               const float* __restrict__ wd, const float* __restrict__ bd,
                                               float* __restrict__ out){
  int tid = (int)threadIdx.x;
  int b = tid >> 2, o = tid & 3;
  const u16* ph = hhi + (((size_t)b * T_ + (T_ - 1)) << 9);
  const u16* pl = hlo + (((size_t)b * T_ + (T_ - 1)) << 9);
  float s = 0.f;
  for (int u = 0; u < 512; ++u){
    float h = bf2f(ph[u]);
    if constexpr (HSLO) h += bf2f(pl[u]);
    s += h * wd[(u << 2) + o];
  }
  out[(b << 2) + o] = s + bd[o];
}

// ---------------------------------------------------------------------------
// Host
// ---------------------------------------------------------------------------
struct HostCtx {
  const float* x; const float* wx1; const float* b1;
  const float* srcW[8];
  const float* Wx4;
  const float* b2; const float* bf3; const float* bb3; const float* b4;
  const float* Wd; const float* bd;
  u16* wth[8]; u16* wtl[8];
  u16* wx4h; u16* wx4l;
  float* xp;
  u16 *PAh, *PAl, *PBh, *PBl, *hc;
  float* cbuf; int* flags;
  float* out;
  int tc, lg;
};

template<int HSLO, int WLO>
static void run_pipeline(const HostCtx& C, hipStream_t stream){
  const u32 scan_lds = WLO ? 139264u : 73728u;
  hipFuncSetAttribute((const void*)&lstm_scan<HSLO,WLO>, hipFuncAttributeMaxDynamicSharedMemorySize, (int)scan_lds);
  hipFuncSetAttribute((const void*)&proj_gemm<HSLO,WLO>, hipFuncAttributeMaxDynamicSharedMemorySize, 131072);

  for (int i = 0; i < 8; ++i)
    hipLaunchKernelGGL(wsplit, dim3(16, 64), dim3(256), 0, stream, C.srcW[i], C.wth[i], WLO ? C.wtl[i] : nullptr, 512);
  hipLaunchKernelGGL(wsplit, dim3(32, 64), dim3(256), 0, stream, C.Wx4, C.wx4h, WLO ? C.wx4l : nullptr, 1024);
  hipLaunchKernelGGL(misc_init, dim3(32), dim3(256), 0, stream, C.flags);

  const int tc = C.tc, lg = C.lg, NC = 512 / tc, sb = 7 - lg;
  int ep = 0;

  auto scan = [&](int wi, u16* hsh_, u16* hsl_, int t0, int dir, int first){
    ScanArgs sa;
    sa.wh_hi = C.wth[wi]; sa.wh_lo = C.wtl[wi]; sa.xp = C.xp;
    sa.hs_hi = hsh_; sa.hs_lo = hsl_; sa.hc = C.hc;
    sa.cbuf = C.cbuf; sa.flags = C.flags;
    sa.t0 = t0; sa.dir = dir; sa.nsteps = tc; sa.first = first; sa.ep0 = ep; sa.lg = lg;
    void* args[] = { &sa };
    hipLaunchCooperativeKernel((const void*)&lstm_scan<HSLO,WLO>, dim3(256), dim3(512), args, scan_lds, stream);
    ep += tc + (first ? 1 : 0);
  };
  auto proj = [&](const u16* ah_, const u16* al_, const u16* wh_, const u16* wl_, long wstr,
                  const float* bias_, int t0, int dir, int accum){
    ProjArgs pa;
    pa.ah = ah_; pa.al = al_; pa.wh = wh_; pa.wl = wl_; pa.wstride = wstr;
    pa.bias = bias_; pa.xp = C.xp; pa.t0 = t0; pa.dir = dir; pa.accum = accum; pa.lg = lg; pa.sb = sb;
    hipLaunchKernelGGL(HIP_KERNEL_NAME(proj_gemm<HSLO,WLO>), dim3(tc, 16), dim3(256), 131072, stream, pa);
  };

  // L1
  for (int c = 0; c < NC; ++c){
    hipLaunchKernelGGL(xproj1, dim3(1024), dim3(256), 0, stream, C.x, C.wx1, C.b1, C.xp, c * tc, lg);
    scan(0, C.PAh, C.PAl, c * tc, 1, c == 0);
  }
  // L2
  for (int c = 0; c < NC; ++c){
    proj(C.PAh, C.PAl, C.wth[1], C.wtl[1], 512, C.b2, c * tc, 1, 0);
    scan(2, C.PAh, C.PAl, c * tc, 1, c == 0);
  }
  // L3 forward
  for (int c = 0; c < NC; ++c){
    proj(C.PAh, C.PAl, C.wth[3], C.wtl[3], 512, C.bf3, c * tc, 1, 0);
    scan(4, C.PBh, C.PBl, c * tc, 1, c == 0);
  }
  // L3 backward
  for (int c = 0; c < NC; ++c){
    int t0 = 511 - c * tc;
    proj(C.PAh, C.PAl, C.wth[5], C.wtl[5], 512, C.bb3, t0, -1, 0);
    scan(6, C.PAh, C.PAl, t0, -1, c == 0);
  }
  // L4
  for (int c = 0; c < NC; ++c){
    proj(C.PBh, C.PBl, C.wx4h, C.wx4l, 1024, C.b4, c * tc, 1, 0);
    proj(C.PAh, C.PAl, C.wx4h + 512, WLO ? (C.wx4l + 512) : nullptr, 1024, nullptr, c * tc, 1, 1);
    scan(7, C.PBh, C.PBl, c * tc, 1, c == 0);
  }
  hipLaunchKernelGGL(HIP_KERNEL_NAME(dense_k<HSLO>), dim3(1), dim3(512), 0, stream, C.PBh, C.PBl, C.Wd, C.bd, C.out);
}

extern "C" void kernel_launch(void* const* d_in, const int* in_sizes, int n_in,
                              void* d_out, int out_size, void* d_ws, size_t ws_size,
                              hipStream_t stream){
  (void)in_sizes; (void)n_in; (void)out_size;
  HostCtx C;
  C.x   = (const float*)d_in[0];
  C.wx1 = (const float*)d_in[1];
  C.b1  = (const float*)d_in[3];
  C.srcW[0] = (const float*)d_in[2];   // Wh1
  C.srcW[1] = (const float*)d_in[4];   // Wx2
  C.srcW[2] = (const float*)d_in[5];   // Wh2
  C.srcW[3] = (const float*)d_in[7];   // Wxf3
  C.srcW[4] = (const float*)d_in[8];   // Whf3
  C.srcW[5] = (const float*)d_in[10];  // Wxb3
  C.srcW[6] = (const float*)d_in[11];  // Whb3
  C.srcW[7] = (const float*)d_in[14];  // Wh4
  C.b2  = (const float*)d_in[6];
  C.bf3 = (const float*)d_in[9];
  C.bb3 = (const float*)d_in[12];
  C.Wx4 = (const float*)d_in[13];
  C.b4  = (const float*)d_in[15];
  C.Wd  = (const float*)d_in[16];
  C.bd  = (const float*)d_in[17];
  C.out = (float*)d_out;

  struct Tier { int tc, hslo, wlo; };
  const Tier tiers[5] = { {128,1,1}, {64,1,1}, {64,0,1}, {32,0,1}, {32,0,0} };

  auto layout = [&](Tier t)->size_t{
    size_t off = 0;
    auto alloc = [&](size_t sz)->char*{
      char* pp = (char*)d_ws + off; off += sz; off = (off + 255) & ~(size_t)255; return pp;
    };
    for (int i = 0; i < 8; ++i){
      C.wth[i] = (u16*)alloc(2097152);
      C.wtl[i] = t.wlo ? (u16*)alloc(2097152) : nullptr;
    }
    C.wx4h = (u16*)alloc(4194304);
    C.wx4l = t.wlo ? (u16*)alloc(4194304) : nullptr;
    C.xp = (float*)alloc((size_t)B_ * t.tc * 2048 * 4);
    C.PAh = (u16*)alloc(67108864);
    C.PAl = t.hslo ? (u16*)alloc(67108864) : nullptr;
    C.PBh = (u16*)alloc(67108864);
    C.PBl = t.hslo ? (u16*)alloc(67108864) : nullptr;
    C.hc  = (u16*)alloc(524288);
    C.cbuf = (float*)alloc(262144);
    C.flags = (int*)alloc(32768);
    return off;
  };

  int ti = 0;
  for (; ti < 5; ++ti){
    if (layout(tiers[ti]) <= ws_size) break;
  }
  if (ti == 5){
    hipLaunchKernelGGL(diag_k, dim3(1), dim3(512), 0, stream, (float*)d_out, (float)(ws_size >> 20));
    return;
  }
  Tier t = tiers[ti];
  C.tc = t.tc;
  C.lg = (t.tc == 128) ? 7 : (t.tc == 64) ? 6 : 5;

  if (t.hslo)      run_pipeline<1,1>(C, stream);
  else if (t.wlo)  run_pipeline<0,1>(C, stream);
  else             run_pipeline<0,0>(C, stream);
}

// Round 7
// 17315.686 us; speedup vs baseline: 4.1426x; 1.1137x over previous
//
#include <hip/hip_runtime.h>

// ---------------------------------------------------------------------------
// Shapes
// ---------------------------------------------------------------------------
#define B_  128
#define T_  512

typedef unsigned short u16;
typedef unsigned int   u32;
typedef __attribute__((ext_vector_type(8))) __bf16 bf16x8;
typedef __attribute__((ext_vector_type(4))) float  f32x4;

static __device__ __forceinline__ u16 f2bf(float f){
  u32 u = __float_as_uint(f);
  return (u16)((u + 0x7fffu + ((u >> 16) & 1u)) >> 16);
}
static __device__ __forceinline__ float bf2f(u16 s){ return __uint_as_float(((u32)s) << 16); }

static __device__ __forceinline__ void gll16(const void* g, void* l){
  __builtin_amdgcn_global_load_lds((const __attribute__((address_space(1))) u32*)g,
                                   (__attribute__((address_space(3))) u32*)l, 16, 0, 0);
}

// LLC-coherent (cache-bypassing) 16B load with immediate offset
template<int OFF>
static __device__ __forceinline__ bf16x8 ld16sc(const char* p){
  bf16x8 r;
  asm volatile("global_load_dwordx4 %0, %1, off offset:%2 sc0 sc1"
               : "=v"(r) : "v"(p), "i"(OFF));
  return r;
}
// LLC-coherent 2B store
static __device__ __forceinline__ void st16sc(char* p, u32 v){
  asm volatile("global_store_short %0, %1, off sc0 sc1" :: "v"(p), "v"(v) : "memory");
}

// ---------------------------------------------------------------------------
// Weight prep: W[K][2048] f32 -> transposed hi/lo bf16 planes [2048][K]
// ---------------------------------------------------------------------------
__global__ __launch_bounds__(256) void wsplit(const float* __restrict__ src,
                                              u16* __restrict__ dhi, u16* __restrict__ dlo, int K){
  __shared__ float t[32][33];
  const int k0 = (int)blockIdx.x << 5, j0 = (int)blockIdx.y << 5;
  const int tx = (int)threadIdx.x & 31, ty = (int)threadIdx.x >> 5;
#pragma unroll
  for (int i = 0; i < 4; ++i){
    int k = ty + (i << 3);
    t[k][tx] = src[(size_t)(k0 + k) * 2048 + j0 + tx];
  }
  __syncthreads();
#pragma unroll
  for (int i = 0; i < 4; ++i){
    int j = ty + (i << 3);
    float v = t[tx][j];
    u16 hi = f2bf(v);
    size_t di = (size_t)(j0 + j) * K + k0 + tx;
    dhi[di] = hi;
    if (dlo) dlo[di] = f2bf(v - bf2f(hi));
  }
}

__global__ void misc_init(int* f){
  __hip_atomic_store(f + (int)blockIdx.x * 256 + (int)threadIdx.x, 0,
                     __ATOMIC_RELAXED, __HIP_MEMORY_SCOPE_AGENT);
}

__global__ void diag_k(float* out, float v){ if (threadIdx.x < 512) out[threadIdx.x] = v; }

// ---------------------------------------------------------------------------
// Projection GEMM: xp rows (+)= A rows @ W + bias. 128x128 tile, BK=32,
// double-buffered LDS 2x32KB -> 2 blocks/CU.
// ---------------------------------------------------------------------------
struct ProjArgs {
  const u16* ah; const u16* al;
  const u16* wh; const u16* wl;
  long wstride;
  const float* bias;
  float* xp;
  int t0, dir, accum, lg, sb;
};

template<int HSLO, int WLO>
__global__ __launch_bounds__(256, 2) void proj_gemm(ProjArgs p){
  extern __shared__ char smem[];          // 2 x 32768
  const int mt = (int)blockIdx.x;
  const int nt = (int)blockIdx.y;
  const int tid = (int)threadIdx.x;
  const int w = tid >> 6, lane = tid & 63;
  const int wm = w & 1, wn = w >> 1;
  const int l15 = lane & 15, l4 = lane >> 4;
  const int tcm1 = (1 << p.lg) - 1;
  const int b0 = mt << p.sb;

  f32x4 acc[4][4];
#pragma unroll
  for (int m2 = 0; m2 < 4; ++m2)
#pragma unroll
    for (int n2 = 0; n2 < 4; ++n2) acc[m2][n2] = (f32x4){0.f,0.f,0.f,0.f};

  const u16* gsrc = nullptr;
  if (w == 0) gsrc = p.ah;
  else if (w == 1) { if constexpr (HSLO) gsrc = p.al; }
  else if (w == 2) gsrc = p.wh;
  else { if constexpr (WLO) gsrc = p.wl; }

  auto do_stage = [&](int ks, int buf){
    if (!gsrc) return;
    char* base = smem + (buf << 15) + (w << 13);
#pragma unroll
    for (int ii = 0; ii < 8; ++ii){
      int r = (ii << 4) + (lane >> 2);
      int co = ((lane & 3) << 4) ^ ((r & 3) << 4);
      size_t rowoff;
      if (w < 2){
        int grow = (b0 + (r >> p.lg)) * T_ + p.t0 + p.dir * (r & tcm1);
        rowoff = ((size_t)grow) << 10;
      } else {
        rowoff = ((size_t)((nt << 7) + r)) * ((size_t)p.wstride << 1);
      }
      gll16((const char*)gsrc + rowoff + (ks << 6) + co, base + (ii << 10));
    }
  };

  do_stage(0, 0);
  for (int ks = 0; ks < 16; ++ks){
    __syncthreads();                       // drains vmcnt(0): buf[ks&1] ready
    if (ks < 15) do_stage(ks + 1, (ks + 1) & 1);
    const char* bb = smem + ((ks & 1) << 15);
    const char* Ah = bb;
    const char* Al = bb + 8192;
    const char* Wh = bb + 16384;
    const char* Wl = bb + 24576;
    bf16x8 ahf[4], alf[4];
#pragma unroll
    for (int m2 = 0; m2 < 4; ++m2){
      int r = (wm << 6) + (m2 << 4) + l15;
      int off = (r << 6) + ((l4 << 4) ^ ((r & 3) << 4));
      ahf[m2] = *(const bf16x8*)(Ah + off);
      if constexpr (HSLO) alf[m2] = *(const bf16x8*)(Al + off);
    }
#pragma unroll
    for (int n2 = 0; n2 < 4; ++n2){
      int cl = (wn << 6) + (n2 << 4) + l15;
      int off = (cl << 6) + ((l4 << 4) ^ ((cl & 3) << 4));
      bf16x8 bh = *(const bf16x8*)(Wh + off);
      bf16x8 bl;
      if constexpr (WLO) bl = *(const bf16x8*)(Wl + off);
#pragma unroll
      for (int m2 = 0; m2 < 4; ++m2){
        acc[m2][n2] = __builtin_amdgcn_mfma_f32_16x16x32_bf16(ahf[m2], bh, acc[m2][n2], 0,0,0);
        if constexpr (WLO)
          acc[m2][n2] = __builtin_amdgcn_mfma_f32_16x16x32_bf16(ahf[m2], bl, acc[m2][n2], 0,0,0);
        if constexpr (HSLO)
          acc[m2][n2] = __builtin_amdgcn_mfma_f32_16x16x32_bf16(alf[m2], bh, acc[m2][n2], 0,0,0);
      }
    }
  }
#pragma unroll
  for (int n2 = 0; n2 < 4; ++n2){
    int gcol = (nt << 7) + (wn << 6) + (n2 << 4) + l15;
    float bs = p.bias ? p.bias[gcol] : 0.f;
#pragma unroll
    for (int m2 = 0; m2 < 4; ++m2){
#pragma unroll
      for (int i = 0; i < 4; ++i){
        int r = (wm << 6) + (m2 << 4) + (l4 << 2) + i;
        size_t idx = (((size_t)(mt << 7) + r) << 11) + gcol;
        float v = acc[m2][n2][i] + bs;
        if (p.accum) v += p.xp[idx];
        p.xp[idx] = v;
      }
    }
  }
}

// ---------------------------------------------------------------------------
// Persistent LSTM scan v4 (non-cooperative): fence-free LLC exchange,
// prefetched gate inputs, hs stores off the critical path.
// 8 bgs(16 rows) x 32 WGs(16 units), 512 thr/WG, grid 256 <= 256 CUs.
// ---------------------------------------------------------------------------
struct ScanArgs {
  const u16* wh_hi; const u16* wh_lo;
  const float* xp;
  const float* x; const float* wx1; const float* b1;   // L1 inline path
  u16* hs_hi; u16* hs_lo;
  u16* hc;                    // [2][B][2][512] u16
  float* cbuf;
  int* flags;                 // [8][32] slots, 128B apart
  int t0, dir, nsteps, first, ep0, lg, is1;
};

template<int HSLO, int WLO>
__global__ __launch_bounds__(512, 1) void lstm_scan(ScanArgs a){
  extern __shared__ char smem[];
  char* whh = smem;
  char* whl = smem + 65536;
  float* zb = (float*)(smem + (WLO ? 131072 : 65536));   // [2][16][64]

  const int bid = (int)blockIdx.x;
  const int bg = bid & 7, wg = bid >> 3;
  const int b0 = bg << 4, u0 = wg << 4;
  const int tid = (int)threadIdx.x;
  const int w = tid >> 6, lane = tid & 63;
  const int ct = w >> 1, kh = w & 1;
  const int l15 = lane & 15, l4 = lane >> 4;
  int* fl_my = a.flags + (bg << 10) + (wg << 5);
  char* hc8 = (char*)a.hc;

  // stage Wh slice once (local col c -> global col (c/16)*512 + u0 + c%16)
#pragma unroll
  for (int i = 0; i < 8; ++i){
    int c = (w << 3) + i;
    int gc = ((c >> 4) << 9) + u0 + (c & 15);
    int co = (lane << 4) ^ ((c & 7) << 4);
    gll16((const char*)a.wh_hi + ((size_t)gc << 10) + co, whh + (c << 10));
    if constexpr (WLO)
      gll16((const char*)a.wh_lo + ((size_t)gc << 10) + co, whl + (c << 10));
  }
  asm volatile("s_waitcnt vmcnt(0)" ::: "memory");
  __syncthreads();

  const int row = (tid >> 4) & 15, uu = tid & 15;
  const int gu = u0 + uu;
  int ep = a.ep0;
  float c_reg = 0.f;

  auto barrier_wait = [&](int target){
    if (tid == 0)
      __hip_atomic_store(fl_my, target, __ATOMIC_RELAXED, __HIP_MEMORY_SCOPE_AGENT);
    if (w == 0){
      const int* f = a.flags + (bg << 10) + ((lane & 31) << 5);
      while (1){
        int v = __hip_atomic_load(f, __ATOMIC_RELAXED, __HIP_MEMORY_SCOPE_AGENT);
        if (__all(v >= target)) break;
        __builtin_amdgcn_s_sleep(2);
      }
    }
  };

  if (a.first){
    if (tid < 256){
      int pz = a.t0 & 1;
      char* wb = hc8 + ((size_t)pz << 18) + ((size_t)(b0 + row) << 11) + ((size_t)gu << 1);
      st16sc(wb, 0);
      st16sc(wb + 1024, 0);
    }
    asm volatile("s_waitcnt vmcnt(0)" ::: "memory");
    __syncthreads();
    barrier_wait(++ep);
    __syncthreads();
  } else if (tid < 256){
    c_reg = a.cbuf[((size_t)(b0 + row) << 9) + gu];
  }

  // L1 inline projection constants (loop-invariant -> registers)
  float w1r[16], b1r[4];
  if (a.is1 && tid < 256){
#pragma unroll
    for (int g = 0; g < 4; ++g){
      int cc = (g << 9) + gu;
      b1r[g] = a.b1[cc];
#pragma unroll
      for (int f4 = 0; f4 < 4; ++f4) w1r[(g << 2) + f4] = a.wx1[(f4 << 11) + cc];
    }
  }

  // per-lane fragment base (within a parity buffer)
  const size_t frag_off = ((size_t)(b0 + l15) << 11) + (kh << 9) + (l4 << 4);
  const int c = (ct << 4) + l15;
  const int cswz = (c & 7) << 4;

  // prefetch gate inputs for tt=0
  float pxg0 = 0.f, pxg1 = 0.f, pxg2 = 0.f, pxg3 = 0.f;
  float4 pxw = {0.f,0.f,0.f,0.f};
  auto issue_xg = [&](int tt){
    if (tid < 256){
      int gt = a.t0 + a.dir * tt;
      if (a.is1){
        pxw = *(const float4*)(a.x + (((size_t)(b0 + row) * T_ + gt) << 2));
      } else {
        const float* xr = a.xp + (((size_t)(((b0 + row) << a.lg) + tt)) << 11) + gu;
        pxg0 = xr[0]; pxg1 = xr[512]; pxg2 = xr[1024]; pxg3 = xr[1536];
      }
    }
  };
  issue_xg(0);

  for (int tt = 0; tt < a.nsteps; ++tt){
    int gt = a.t0 + a.dir * tt;
    int par = gt & 1, pn = par ^ 1;

    // A-fragments straight from LLC (hi + lo), sc0 sc1
    const char* fb = hc8 + ((size_t)par << 18) + frag_off;
    bf16x8 fh[8] = { ld16sc<   0>(fb), ld16sc<  64>(fb), ld16sc< 128>(fb), ld16sc< 192>(fb),
                     ld16sc< 256>(fb), ld16sc< 320>(fb), ld16sc< 384>(fb), ld16sc< 448>(fb) };
    bf16x8 fL[8] = { ld16sc<1024>(fb), ld16sc<1088>(fb), ld16sc<1152>(fb), ld16sc<1216>(fb),
                     ld16sc<1280>(fb), ld16sc<1344>(fb), ld16sc<1408>(fb), ld16sc<1472>(fb) };
    asm volatile("s_waitcnt vmcnt(0)" ::: "memory");
    __builtin_amdgcn_sched_barrier(0);

    // consume prefetched gate inputs
    float xg0 = 0.f, xg1 = 0.f, xg2 = 0.f, xg3 = 0.f;
    if (tid < 256){
      if (a.is1){
        xg0 = b1r[0] + pxw.x*w1r[0]  + pxw.y*w1r[1]  + pxw.z*w1r[2]  + pxw.w*w1r[3];
        xg1 = b1r[1] + pxw.x*w1r[4]  + pxw.y*w1r[5]  + pxw.z*w1r[6]  + pxw.w*w1r[7];
        xg2 = b1r[2] + pxw.x*w1r[8]  + pxw.y*w1r[9]  + pxw.z*w1r[10] + pxw.w*w1r[11];
        xg3 = b1r[3] + pxw.x*w1r[12] + pxw.y*w1r[13] + pxw.z*w1r[14] + pxw.w*w1r[15];
      } else {
        xg0 = pxg0; xg1 = pxg1; xg2 = pxg2; xg3 = pxg3;
      }
    }
    // issue prefetch for tt+1 (hidden under MFMA + gates + barrier)
    if (tt + 1 < a.nsteps) issue_xg(tt + 1);

    f32x4 acc0 = (f32x4){0.f,0.f,0.f,0.f};
    f32x4 acc1 = (f32x4){0.f,0.f,0.f,0.f};
#pragma unroll
    for (int j = 0; j < 8; ++j){
      int ko = ((((kh << 3) + j) << 6) + (l4 << 4));
      bf16x8 bh = *(const bf16x8*)(whh + (c << 10) + (ko ^ cswz));
      acc0 = __builtin_amdgcn_mfma_f32_16x16x32_bf16(fh[j], bh, acc0, 0,0,0);
      if constexpr (WLO){
        bf16x8 bl = *(const bf16x8*)(whl + (c << 10) + (ko ^ cswz));
        acc0 = __builtin_amdgcn_mfma_f32_16x16x32_bf16(fh[j], bl, acc0, 0,0,0);
      }
      acc1 = __builtin_amdgcn_mfma_f32_16x16x32_bf16(fL[j], bh, acc1, 0,0,0);
    }
    acc0[0] += acc1[0]; acc0[1] += acc1[1]; acc0[2] += acc1[2]; acc0[3] += acc1[3];
#pragma unroll
    for (int i = 0; i < 4; ++i)
      zb[(kh << 10) + (((l4 << 2) + i) << 6) + c] = acc0[i];
    __syncthreads();

    u16 hh = 0, hl = 0;
    if (tid < 256){
      int zo_ = (row << 6) + uu;
      float zi = zb[zo_]      + zb[1024 + zo_]      + xg0;
      float zf = zb[zo_ + 16] + zb[1024 + zo_ + 16] + xg1;
      float zg = zb[zo_ + 32] + zb[1024 + zo_ + 32] + xg2;
      float zo = zb[zo_ + 48] + zb[1024 + zo_ + 48] + xg3;
      float ig = 1.f / (1.f + expf(-zi));
      float fg = 1.f / (1.f + expf(-zf));
      float gg = tanhf(zg);
      float og = 1.f / (1.f + expf(-zo));
      c_reg = fg * c_reg + ig * gg;
      float h = og * tanhf(c_reg);
      hh = f2bf(h);
      hl = f2bf(h - bf2f(hh));
      char* wb = hc8 + ((size_t)pn << 18) + ((size_t)(b0 + row) << 11) + ((size_t)gu << 1);
      st16sc(wb, (u32)hh);
      st16sc(wb + 1024, (u32)hl);
    }
    asm volatile("s_waitcnt vmcnt(0)" ::: "memory");   // hc at LLC before flag
    __syncthreads();
    ++ep;
    barrier_wait(ep);                                   // tid0 publishes, wave0 polls
    if (tid < 256){                                     // hs stores off critical path
      size_t si = (((size_t)(b0 + row) * T_ + gt) << 9) + gu;
      a.hs_hi[si] = hh;
      if constexpr (HSLO) a.hs_lo[si] = hl;
    }
    __syncthreads();
  }
  if (tid < 256) a.cbuf[((size_t)(b0 + row) << 9) + gu] = c_reg;
}

// ---------------------------------------------------------------------------
// Final dense head
// ---------------------------------------------------------------------------
template<int HSLO>
__global__ __launch_bounds__(512) void dense_k(const u16* __restrict__ hhi, const u16* __restrict__ hlo,
                                               const float* __restrict__ wd, const float* __restrict__ bd,
                                               float* __restrict__ out){
  int tid = (int)threadIdx.x;
  int b = tid >> 2, o = tid & 3;
  const u16* ph = hhi + (((size_t)b * T_ + (T_ - 1)) << 9);
  const u16* pl = hlo + (((size_t)b * T_ + (T_ - 1)) << 9);
  float s = 0.f;
  for (int u = 0; u < 512; ++u){
    float h = bf2f(ph[u]);
    if constexpr (HSLO) h += bf2f(pl[u]);
    s += h * wd[(u << 2) + o];
  }
  out[(b << 2) + o] = s + bd[o];
}

// ---------------------------------------------------------------------------
// Host
// ---------------------------------------------------------------------------
struct HostCtx {
  const float* x; const float* wx1; const float* b1;
  const float* srcW[8];
  const float* Wx4;
  const float* b2; const float* bf3; const float* bb3; const float* b4;
  const float* Wd; const float* bd;
  u16* wth[8]; u16* wtl[8];
  u16* wx4h; u16* wx4l;
  float* xp;
  u16 *PAh, *PAl, *PBh, *PBl, *hc;
  float* cbuf; int* flags;
  float* out;
  int tc, lg;
};

template<int HSLO, int WLO>
static void run_pipeline(const HostCtx& C, hipStream_t stream){
  const u32 scan_lds = WLO ? 139264u : 73728u;
  hipFuncSetAttribute((const void*)&lstm_scan<HSLO,WLO>, hipFuncAttributeMaxDynamicSharedMemorySize, (int)scan_lds);
  hipFuncSetAttribute((const void*)&proj_gemm<HSLO,WLO>, hipFuncAttributeMaxDynamicSharedMemorySize, 65536);

  for (int i = 0; i < 8; ++i)
    hipLaunchKernelGGL(wsplit, dim3(16, 64), dim3(256), 0, stream, C.srcW[i], C.wth[i], WLO ? C.wtl[i] : nullptr, 512);
  hipLaunchKernelGGL(wsplit, dim3(32, 64), dim3(256), 0, stream, C.Wx4, C.wx4h, WLO ? C.wx4l : nullptr, 1024);
  hipLaunchKernelGGL(misc_init, dim3(32), dim3(256), 0, stream, C.flags);

  const int tc = C.tc, lg = C.lg, NC = 512 / tc, sb = 7 - lg;
  int ep = 0;

  auto scan = [&](int wi, int is1, int nsteps, u16* hsh_, u16* hsl_, int t0, int dir, int first){
    ScanArgs sa;
    sa.wh_hi = C.wth[wi]; sa.wh_lo = C.wtl[wi]; sa.xp = C.xp;
    sa.x = C.x; sa.wx1 = C.wx1; sa.b1 = C.b1;
    sa.hs_hi = hsh_; sa.hs_lo = hsl_; sa.hc = C.hc;
    sa.cbuf = C.cbuf; sa.flags = C.flags;
    sa.t0 = t0; sa.dir = dir; sa.nsteps = nsteps; sa.first = first; sa.ep0 = ep; sa.lg = lg; sa.is1 = is1;
    hipLaunchKernelGGL(HIP_KERNEL_NAME(lstm_scan<HSLO,WLO>), dim3(256), dim3(512), scan_lds, stream, sa);
    ep += nsteps + (first ? 1 : 0);
  };
  auto proj = [&](const u16* ah_, const u16* al_, const u16* wh_, const u16* wl_, long wstr,
                  const float* bias_, int t0, int dir, int accum){
    ProjArgs pa;
    pa.ah = ah_; pa.al = al_; pa.wh = wh_; pa.wl = wl_; pa.wstride = wstr;
    pa.bias = bias_; pa.xp = C.xp; pa.t0 = t0; pa.dir = dir; pa.accum = accum; pa.lg = lg; pa.sb = sb;
    hipLaunchKernelGGL(HIP_KERNEL_NAME(proj_gemm<HSLO,WLO>), dim3(tc, 16), dim3(256), 65536, stream, pa);
  };

  // L1: single 512-step scan with inline x-projection
  scan(0, 1, T_, C.PAh, C.PAl, 0, 1, 1);
  // L2
  for (int c = 0; c < NC; ++c){
    proj(C.PAh, C.PAl, C.wth[1], C.wtl[1], 512, C.b2, c * tc, 1, 0);
    scan(2, 0, tc, C.PAh, C.PAl, c * tc, 1, c == 0);
  }
  // L3 forward
  for (int c = 0; c < NC; ++c){
    proj(C.PAh, C.PAl, C.wth[3], C.wtl[3], 512, C.bf3, c * tc, 1, 0);
    scan(4, 0, tc, C.PBh, C.PBl, c * tc, 1, c == 0);
  }
  // L3 backward
  for (int c = 0; c < NC; ++c){
    int t0 = 511 - c * tc;
    proj(C.PAh, C.PAl, C.wth[5], C.wtl[5], 512, C.bb3, t0, -1, 0);
    scan(6, 0, tc, C.PAh, C.PAl, t0, -1, c == 0);
  }
  // L4
  for (int c = 0; c < NC; ++c){
    proj(C.PBh, C.PBl, C.wx4h, C.wx4l, 1024, C.b4, c * tc, 1, 0);
    proj(C.PAh, C.PAl, C.wx4h + 512, WLO ? (C.wx4l + 512) : nullptr, 1024, nullptr, c * tc, 1, 1);
    scan(7, 0, tc, C.PBh, C.PBl, c * tc, 1, c == 0);
  }
  hipLaunchKernelGGL(HIP_KERNEL_NAME(dense_k<HSLO>), dim3(1), dim3(512), 0, stream, C.PBh, C.PBl, C.Wd, C.bd, C.out);
}

extern "C" void kernel_launch(void* const* d_in, const int* in_sizes, int n_in,
                              void* d_out, int out_size, void* d_ws, size_t ws_size,
                              hipStream_t stream){
  (void)in_sizes; (void)n_in; (void)out_size;
  HostCtx C;
  C.x   = (const float*)d_in[0];
  C.wx1 = (const float*)d_in[1];
  C.b1  = (const float*)d_in[3];
  C.srcW[0] = (const float*)d_in[2];   // Wh1
  C.srcW[1] = (const float*)d_in[4];   // Wx2
  C.srcW[2] = (const float*)d_in[5];   // Wh2
  C.srcW[3] = (const float*)d_in[7];   // Wxf3
  C.srcW[4] = (const float*)d_in[8];   // Whf3
  C.srcW[5] = (const float*)d_in[10];  // Wxb3
  C.srcW[6] = (const float*)d_in[11];  // Whb3
  C.srcW[7] = (const float*)d_in[14];  // Wh4
  C.b2  = (const float*)d_in[6];
  C.bf3 = (const float*)d_in[9];
  C.bb3 = (const float*)d_in[12];
  C.Wx4 = (const float*)d_in[13];
  C.b4  = (const float*)d_in[15];
  C.Wd  = (const float*)d_in[16];
  C.bd  = (const float*)d_in[17];
  C.out = (float*)d_out;

  struct Tier { int tc, hslo, wlo; };
  const Tier tiers[5] = { {128,1,1}, {64,1,1}, {64,0,1}, {32,0,1}, {32,0,0} };

  auto layout = [&](Tier t)->size_t{
    size_t off = 0;
    auto alloc = [&](size_t sz)->char*{
      char* pp = (char*)d_ws + off; off += sz; off = (off + 255) & ~(size_t)255; return pp;
    };
    for (int i = 0; i < 8; ++i){
      C.wth[i] = (u16*)alloc(2097152);
      C.wtl[i] = t.wlo ? (u16*)alloc(2097152) : nullptr;
    }
    C.wx4h = (u16*)alloc(4194304);
    C.wx4l = t.wlo ? (u16*)alloc(4194304) : nullptr;
    C.xp = (float*)alloc((size_t)B_ * t.tc * 2048 * 4);
    C.PAh = (u16*)alloc(67108864);
    C.PAl = t.hslo ? (u16*)alloc(67108864) : nullptr;
    C.PBh = (u16*)alloc(67108864);
    C.PBl = t.hslo ? (u16*)alloc(67108864) : nullptr;
    C.hc  = (u16*)alloc(524288);
    C.cbuf = (float*)alloc(262144);
    C.flags = (int*)alloc(32768);
    return off;
  };

  int ti = 0;
  for (; ti < 5; ++ti){
    if (layout(tiers[ti]) <= ws_size) break;
  }
  if (ti == 5){
    hipLaunchKernelGGL(diag_k, dim3(1), dim3(512), 0, stream, (float*)d_out, (float)(ws_size >> 20));
    return;
  }
  Tier t = tiers[ti];
  C.tc = t.tc;
  C.lg = (t.tc == 128) ? 7 : (t.tc == 64) ? 6 : 5;

  if (t.hslo)      run_pipeline<1,1>(C, stream);
  else if (t.wlo)  run_pipeline<0,1>(C, stream);
  else             run_pipeline<0,0>(C, stream);
}